// Round 7
// baseline (979.959 us; speedup 1.0000x reference)
//
#include <hip/hip_runtime.h>
#include <math.h>

#define DM 256          // d_model
#define NS 64           // N state
#define SP 128          // spatial H == W

typedef __attribute__((ext_vector_type(8))) short bf16x8;
typedef __attribute__((ext_vector_type(4))) float f32x4;

__device__ __forceinline__ float gelu_f(float x) {
    float x3 = x * x * x;
    return 0.5f * x * (1.0f + tanhf(0.7978845608028654f * (x + 0.044715f * x3)));
}
__device__ __forceinline__ float sigmoid_f(float x) {
    return 1.0f / (1.0f + expf(-x));
}
__device__ __forceinline__ unsigned short f2bf(float f) {   // RNE f32->bf16
    unsigned u = __float_as_uint(f);
    u += 0x7fff + ((u >> 16) & 1);
    return (unsigned short)(u >> 16);
}
__device__ __forceinline__ float bf2f(unsigned short b) {
    return __uint_as_float(((unsigned)b) << 16);
}

// ---------------------------------------------------------------------------
// S4D tap generation -> Kd[la][d][q] fp32 (verified).
// ---------------------------------------------------------------------------
__global__ __launch_bounds__(128) void gen_k_kernel(
        const float* __restrict__ log_dt, const float* __restrict__ logA_re,
        const float* __restrict__ A_im,   const float* __restrict__ C_re,
        const float* __restrict__ C_im,   float* __restrict__ Kd) {
    int blk = blockIdx.x;
    int d  = blk & (DM - 1);
    int la = blk >> 8;
    int q  = threadIdx.x;
    __shared__ float s_cbr[NS], s_cbi[NS], s_dr[NS], s_di[NS];
    int pbase = (la * DM + d) * NS;
    float dt = expf(log_dt[la * DM + d]);
    if (q < NS) {
        int n = q;
        float ar = -expf(logA_re[pbase + n]);
        float ai = A_im[pbase + n];
        float dr = dt * ar, di = dt * ai;
        float er = expf(dr);
        float sn, cs;
        sincosf(di, &sn, &cs);
        float nr = er * cs - 1.0f, ni = er * sn;
        float inv = 1.0f / (ar * ar + ai * ai);
        float br = (nr * ar + ni * ai) * inv;
        float bi = (ni * ar - nr * ai) * inv;
        float cr = C_re[pbase + n], ci = C_im[pbase + n];
        s_cbr[n] = cr * br - ci * bi;
        s_cbi[n] = cr * bi + ci * br;
        s_dr[n] = dr;
        s_di[n] = di;
    }
    __syncthreads();
    float fq = (float)q;
    float acc = 0.0f;
    for (int n = 0; n < NS; ++n) {
        float pr = expf(s_dr[n] * fq);
        float sn, cs;
        sincosf(s_di[n] * fq, &sn, &cs);
        acc += s_cbr[n] * (pr * cs) - s_cbi[n] * (pr * sn);
    }
    Kd[((size_t)la * DM + d) * SP + q] = 2.0f * acc;
}

// ---------------------------------------------------------------------------
// Toeplitz build (per layer): Tp[axis][d][i][j] = k[i-j] (j<=i), bf16.
// ---------------------------------------------------------------------------
__global__ __launch_bounds__(256) void toep_kernel(
        const float* __restrict__ Kd, unsigned short* __restrict__ Tp, int l) {
    int blk = blockIdx.x;
    int axis = blk >> 8, d = blk & 255;
    int la = l * 2 + axis;
    __shared__ float kt[SP];
    if (threadIdx.x < SP) kt[threadIdx.x] = Kd[((size_t)la * DM + d) * SP + threadIdx.x];
    __syncthreads();
    size_t bse = ((size_t)axis * DM + d) * 16384;
    for (int e = threadIdx.x; e < 16384; e += 256) {
        int i = e >> 7, j = e & 127;
        Tp[bse + e] = (j <= i) ? f2bf(kt[i - j]) : (unsigned short)0;
    }
}

// ---------------------------------------------------------------------------
// W_out fp32 [l][k=256][n=512] -> Bt bf16 [l][n=512][k=256]
// ---------------------------------------------------------------------------
__global__ __launch_bounds__(256) void prep_b_kernel(
        const float* __restrict__ Wo, unsigned short* __restrict__ Bt) {
    int idx = blockIdx.x * 256 + threadIdx.x;
    int l = idx >> 17, rem = idx & 131071, n = rem >> 8, k = rem & 255;
    Bt[idx] = f2bf(Wo[(size_t)l * 131072 + k * 512 + n]);
}

// ---------------------------------------------------------------------------
// Encoder -> h_g[dg][pos][di] bf16 (group-of-8 channel-major).
// ---------------------------------------------------------------------------
__global__ __launch_bounds__(256) void encode_kernel(
        const float* __restrict__ x, const float* __restrict__ g,
        const float* __restrict__ W_enc, const float* __restrict__ b_enc,
        unsigned short* __restrict__ hg) {
    int pos = blockIdx.x * 4 + (threadIdx.x >> 6);
    int lane = threadIdx.x & 63;
    int d0 = lane * 4;
    float xv = x[pos], gv = g[pos];
    float4 w0 = *(const float4*)(W_enc + d0);
    float4 w1 = *(const float4*)(W_enc + DM + d0);
    float4 bb = *(const float4*)(b_enc + d0);
    float v0 = xv * w0.x + gv * w1.x + bb.x;
    float v1 = xv * w0.y + gv * w1.y + bb.y;
    float v2 = xv * w0.z + gv * w1.z + bb.z;
    float v3 = xv * w0.w + gv * w1.w + bb.w;
    uint2 ov;
    ov.x = (unsigned)f2bf(v0) | ((unsigned)f2bf(v1) << 16);
    ov.y = (unsigned)f2bf(v2) | ((unsigned)f2bf(v3) << 16);
    *(uint2*)(hg + ((size_t)(d0 >> 3) * 65536 + pos) * 8 + (d0 & 7)) = ov;
}

// ---------------------------------------------------------------------------
// Fused separable conv via MFMA (math identical to r6, scheduling fixed):
// 512 thr (8 waves), staging batched 16-deep, Toeplitz B-frags double-buffered
// in registers and prefetched one kk ahead (GEMM1 kk0 issued before staging,
// GEMM2 kk0 during GEMM1 tail). XOR-chunk-swizzled LDS tiles (2-way max).
// ---------------------------------------------------------------------------
__global__ __launch_bounds__(512, 2) void conv_kernel(
        const unsigned short* __restrict__ hg, const unsigned short* __restrict__ Tp,
        unsigned short* __restrict__ Ag, const float* __restrict__ Dsk) {
    __shared__ unsigned short U[128][128];     // [hh][w-chunk ^ (hh&7)]
    __shared__ unsigned short M1T[128][128];   // [w][hh-chunk ^ (w&7)]
    int bid = blockIdx.x;
    int work = (bid & 7) * 128 + (bid >> 3);   // XCD-grouped
    int di = work & 7, rem = work >> 3;
    int b = rem & 3, dg = rem >> 2;
    int d = dg * 8 + di;
    int tid = threadIdx.x;
    int lane = tid & 63, wv = tid >> 6;        // 8 waves
    int lc = lane & 15, g = lane >> 4;

    const unsigned short* TpW = Tp + (size_t)(DM + d) * 16384;  // axis 1 (W)
    const unsigned short* TpH = Tp + (size_t)d * 16384;         // axis 0 (H)

    // GEMM1 kk=0 B-frags issued before staging (latency hides under it)
    bf16x8 bcur[8], bnxt[8];
    #pragma unroll
    for (int ni = 0; ni < 8; ++ni)
        bcur[ni] = *(const bf16x8*)(TpW + (size_t)(ni * 16 + lc) * 128 + g * 8);

    // ---- stage U (16-deep load batches -> 16 outstanding loads)
    {
        const unsigned short* src = hg + ((size_t)dg * 65536 + (size_t)b * 16384) * 8 + di;
        #pragma unroll
        for (int bb2 = 0; bb2 < 2; ++bb2) {
            unsigned short tmp[16];
            #pragma unroll
            for (int q = 0; q < 16; ++q)
                tmp[q] = src[(size_t)((bb2 * 16 + q) * 512 + tid) * 8];
            #pragma unroll
            for (int q = 0; q < 16; ++q) {
                int idx = (bb2 * 16 + q) * 512 + tid;
                int hh = idx >> 7, w = idx & 127;
                U[hh][(((w >> 3) ^ (hh & 7)) << 3) | (w & 7)] = tmp[q];
            }
        }
    }
    __syncthreads();

    // ---- GEMM1: M1[hh,w] = sum_j U[hh,j]*kw[w-j]  -> M1T[w][hh] (LDS)
    {
        f32x4 acc[8];
        #pragma unroll
        for (int ni = 0; ni < 8; ++ni) acc[ni] = (f32x4){0.f, 0.f, 0.f, 0.f};
        #pragma unroll
        for (int kk = 0; kk < 4; ++kk) {
            if (kk < 3) {
                #pragma unroll
                for (int ni = 0; ni < 8; ++ni)
                    bnxt[ni] = *(const bf16x8*)(TpW + (size_t)(ni * 16 + lc) * 128 + (kk + 1) * 32 + g * 8);
            } else {   // prefetch GEMM2's kk=0 frags
                #pragma unroll
                for (int ni = 0; ni < 8; ++ni)
                    bnxt[ni] = *(const bf16x8*)(TpH + (size_t)(ni * 16 + lc) * 128 + g * 8);
            }
            int hh = wv * 16 + lc;
            bf16x8 a = *(const bf16x8*)&U[hh][(((kk * 4 + g) ^ (hh & 7)) << 3)];
            #pragma unroll
            for (int ni = 0; ni < 8; ++ni)
                acc[ni] = __builtin_amdgcn_mfma_f32_16x16x32_bf16(a, bcur[ni], acc[ni], 0, 0, 0);
            #pragma unroll
            for (int ni = 0; ni < 8; ++ni) bcur[ni] = bnxt[ni];
        }
        int hh0 = wv * 16 + g * 4;
        #pragma unroll
        for (int ni = 0; ni < 8; ++ni) {
            int w = ni * 16 + lc;
            ushort4 p;
            p.x = f2bf(acc[ni][0]); p.y = f2bf(acc[ni][1]);
            p.z = f2bf(acc[ni][2]); p.w = f2bf(acc[ni][3]);
            *(ushort4*)&M1T[w][((((hh0 >> 3) ^ (w & 7)) << 3) | (hh0 & 7))] = p;
        }
    }
    __syncthreads();

    // ---- GEMM2: ZT[w,hh] = sum_{h'} M1T[w,h']*kh[hh-h'] ; epilogue + store
    {
        f32x4 acc[8];
        #pragma unroll
        for (int ni = 0; ni < 8; ++ni) acc[ni] = (f32x4){0.f, 0.f, 0.f, 0.f};
        #pragma unroll
        for (int kk = 0; kk < 4; ++kk) {
            if (kk < 3) {
                #pragma unroll
                for (int ni = 0; ni < 8; ++ni)
                    bnxt[ni] = *(const bf16x8*)(TpH + (size_t)(ni * 16 + lc) * 128 + (kk + 1) * 32 + g * 8);
            }
            int w = wv * 16 + lc;
            bf16x8 a = *(const bf16x8*)&M1T[w][(((kk * 4 + g) ^ (w & 7)) << 3)];
            #pragma unroll
            for (int ni = 0; ni < 8; ++ni)
                acc[ni] = __builtin_amdgcn_mfma_f32_16x16x32_bf16(a, bcur[ni], acc[ni], 0, 0, 0);
            #pragma unroll
            for (int ni = 0; ni < 8; ++ni) bcur[ni] = bnxt[ni];
        }
        float dk = Dsk[d];
        int w0 = wv * 16 + g * 4;
        #pragma unroll
        for (int ni = 0; ni < 8; ++ni) {
            int hh = ni * 16 + lc;
            ushort4 hu = *(const ushort4*)&U[hh][((((w0 >> 3) ^ (hh & 7)) << 3) | (w0 & 7))];
            size_t ob = ((size_t)dg * 65536 + (size_t)b * 16384 + (size_t)hh * 128 + w0) * 8 + di;
            Ag[ob]      = f2bf(gelu_f(acc[ni][0] + bf2f(hu.x) * dk));
            Ag[ob + 8]  = f2bf(gelu_f(acc[ni][1] + bf2f(hu.y) * dk));
            Ag[ob + 16] = f2bf(gelu_f(acc[ni][2] + bf2f(hu.z) * dk));
            Ag[ob + 24] = f2bf(gelu_f(acc[ni][3] + bf2f(hu.w) * dk));
        }
    }
}

// ---------------------------------------------------------------------------
// GLU GEMM, barrier/LDS-free, truly-persistent W: wave owns 16 a-cols + 16
// g-cols (wa[8]+wg[8] = 64 VGPR). 4 waves/block; grid = 512 m-blocks x 4
// col-quarters. hp = (A@W_a+b_a)*sigmoid(A@W_g+b_g) + h, pos-major bf16.
// ---------------------------------------------------------------------------
__global__ __launch_bounds__(256, 2) void glu_kernel(
        const unsigned short* __restrict__ Ag, const unsigned short* __restrict__ Bt,
        const unsigned short* __restrict__ hg, unsigned short* __restrict__ hp,
        const float* __restrict__ bo) {
    int tid = threadIdx.x;
    int lane = tid & 63, wv = tid >> 6;        // 4 waves
    int lc = lane & 15, g = lane >> 4;
    int qtr = blockIdx.x & 3;
    int m0 = (blockIdx.x >> 2) * 128;
    int ca = (qtr * 4 + wv) * 16;              // 16 a-cols
    int cg = 256 + ca;                         // matching 16 g-cols

    bf16x8 wa[8], wgf[8];
    #pragma unroll
    for (int kk = 0; kk < 8; ++kk) {
        wa[kk]  = *(const bf16x8*)(Bt + (size_t)(ca + lc) * DM + kk * 32 + g * 8);
        wgf[kk] = *(const bf16x8*)(Bt + (size_t)(cg + lc) * DM + kk * 32 + g * 8);
    }
    float4 ba = *(const float4*)(bo + ca + g * 4);
    float4 bg = *(const float4*)(bo + cg + g * 4);

    bf16x8 af[8];
    #pragma unroll
    for (int kk = 0; kk < 8; ++kk)
        af[kk] = *(const bf16x8*)(Ag + ((size_t)(kk * 4 + g) * 65536 + m0 + lc) * 8);

    int d0 = ca + g * 4;
    size_t hbase = ((size_t)(d0 >> 3) * 65536) * 8 + (d0 & 7);

    #pragma unroll
    for (int s = 0; s < 8; ++s) {
        int pos = m0 + s * 16 + lc;
        uint2 hv = *(const uint2*)(hg + hbase + (size_t)pos * 8);
        f32x4 aa = (f32x4){0.f, 0.f, 0.f, 0.f};
        f32x4 ag = aa;
        #pragma unroll
        for (int kk = 0; kk < 8; ++kk) {
            aa = __builtin_amdgcn_mfma_f32_16x16x32_bf16(wa[kk], af[kk], aa, 0, 0, 0);
            ag = __builtin_amdgcn_mfma_f32_16x16x32_bf16(wgf[kk], af[kk], ag, 0, 0, 0);
            if (s < 7)
                af[kk] = *(const bf16x8*)(Ag + ((size_t)(kk * 4 + g) * 65536 + m0 + (s + 1) * 16 + lc) * 8);
        }
        float hr[4];
        hr[0] = __uint_as_float(hv.x << 16);
        hr[1] = __uint_as_float(hv.x & 0xffff0000u);
        hr[2] = __uint_as_float(hv.y << 16);
        hr[3] = __uint_as_float(hv.y & 0xffff0000u);
        float o[4];
        #pragma unroll
        for (int reg = 0; reg < 4; ++reg)
            o[reg] = (aa[reg] + (&ba.x)[reg]) * sigmoid_f(ag[reg] + (&bg.x)[reg]) + hr[reg];
        uint2 ov;
        ov.x = (unsigned)f2bf(o[0]) | ((unsigned)f2bf(o[1]) << 16);
        ov.y = (unsigned)f2bf(o[2]) | ((unsigned)f2bf(o[3]) << 16);
        *(uint2*)(hp + (size_t)pos * DM + d0) = ov;
    }
}

// ---------------------------------------------------------------------------
// LayerNorm: h_g = LN(hp). Wave = 1 row (pos-major in, group-major out).
// ---------------------------------------------------------------------------
__global__ __launch_bounds__(256) void ln_kernel(
        const unsigned short* __restrict__ hp, unsigned short* __restrict__ hg,
        const float* __restrict__ lnw, const float* __restrict__ lnb) {
    int pos = blockIdx.x * 4 + (threadIdx.x >> 6);
    int lane = threadIdx.x & 63;
    size_t base = (size_t)pos * DM + lane * 4;
    uint2 hv = *(const uint2*)(hp + base);
    float v[4];
    v[0] = __uint_as_float(hv.x << 16);
    v[1] = __uint_as_float(hv.x & 0xffff0000u);
    v[2] = __uint_as_float(hv.y << 16);
    v[3] = __uint_as_float(hv.y & 0xffff0000u);
    float s1 = v[0] + v[1] + v[2] + v[3];
    float s2 = v[0] * v[0] + v[1] * v[1] + v[2] * v[2] + v[3] * v[3];
    #pragma unroll
    for (int off = 1; off < 64; off <<= 1) {
        s1 += __shfl_xor(s1, off);
        s2 += __shfl_xor(s2, off);
    }
    float mean = s1 * (1.0f / 256.0f);
    float var = s2 * (1.0f / 256.0f) - mean * mean;
    float inv = rsqrtf(var + 1e-5f);
    float4 w4 = *(const float4*)(lnw + lane * 4);
    float4 b4 = *(const float4*)(lnb + lane * 4);
    float o0 = (v[0] - mean) * inv * w4.x + b4.x;
    float o1 = (v[1] - mean) * inv * w4.y + b4.y;
    float o2 = (v[2] - mean) * inv * w4.z + b4.z;
    float o3 = (v[3] - mean) * inv * w4.w + b4.w;
    uint2 ov;
    ov.x = (unsigned)f2bf(o0) | ((unsigned)f2bf(o1) << 16);
    ov.y = (unsigned)f2bf(o2) | ((unsigned)f2bf(o3) << 16);
    int d0 = lane * 4;
    *(uint2*)(hg + ((size_t)(d0 >> 3) * 65536 + pos) * 8 + (d0 & 7)) = ov;
}

// ---------------------------------------------------------------------------
// Decoder from h_g.
// ---------------------------------------------------------------------------
__global__ __launch_bounds__(256) void decode_kernel(
        const unsigned short* __restrict__ hg, const float* __restrict__ Wd,
        const float* __restrict__ bd, float* __restrict__ out) {
    int pos = blockIdx.x * 4 + (threadIdx.x >> 6);
    int lane = threadIdx.x & 63;
    int d0 = lane * 4;
    uint2 hv = *(const uint2*)(hg + ((size_t)(d0 >> 3) * 65536 + pos) * 8 + (d0 & 7));
    float4 w4 = *(const float4*)(Wd + d0);
    float s = __uint_as_float(hv.x << 16) * w4.x
            + __uint_as_float(hv.x & 0xffff0000u) * w4.y
            + __uint_as_float(hv.y << 16) * w4.z
            + __uint_as_float(hv.y & 0xffff0000u) * w4.w;
    #pragma unroll
    for (int off = 32; off > 0; off >>= 1) s += __shfl_down(s, off);
    if (lane == 0) out[pos] = s + bd[0];
}

// ---------------------------------------------------------------------------
extern "C" void kernel_launch(void* const* d_in, const int* in_sizes, int n_in,
                              void* d_out, int out_size, void* d_ws, size_t ws_size,
                              hipStream_t stream) {
    const float* x       = (const float*)d_in[0];
    const float* grid    = (const float*)d_in[1];
    const float* W_enc   = (const float*)d_in[2];
    const float* b_enc   = (const float*)d_in[3];
    const float* log_dt  = (const float*)d_in[4];
    const float* logA_re = (const float*)d_in[5];
    const float* A_im    = (const float*)d_in[6];
    const float* C_re    = (const float*)d_in[7];
    const float* C_im    = (const float*)d_in[8];
    const float* Dskip   = (const float*)d_in[9];
    const float* W_out   = (const float*)d_in[10];
    const float* b_out   = (const float*)d_in[11];
    const float* ln_w    = (const float*)d_in[12];
    const float* ln_b    = (const float*)d_in[13];
    const float* W_dec   = (const float*)d_in[14];
    const float* b_dec   = (const float*)d_in[15];

    char* base = (char*)d_ws;
    float*          Kd  = (float*)base;                            //  1,048,576 B
    unsigned short* Bt  = (unsigned short*)(base + 1048576);       //  1,048,576 B
    unsigned short* hg  = (unsigned short*)(base + 2097152);       // 33,554,432 B
    unsigned short* Ag  = (unsigned short*)(base + 35651584);      // 33,554,432 B
    unsigned short* X   = (unsigned short*)(base + 69206016);      // 33,554,432 B
    unsigned short* Tp  = X;      // per-layer Toeplitz (16.78 MB of X)
    unsigned short* hp  = X;      // GLU output (33.55 MB) — time-shared with Tp

    gen_k_kernel<<<dim3(8 * DM), dim3(128), 0, stream>>>(log_dt, logA_re, A_im,
                                                         C_re, C_im, Kd);
    prep_b_kernel<<<dim3(2048), dim3(256), 0, stream>>>(W_out, Bt);
    encode_kernel<<<dim3(16384), dim3(256), 0, stream>>>(x, grid, W_enc, b_enc, hg);

    for (int l = 0; l < 4; ++l) {
        toep_kernel<<<dim3(512), dim3(256), 0, stream>>>(Kd, Tp, l);
        conv_kernel<<<dim3(1024), dim3(512), 0, stream>>>(hg, Tp, Ag,
                                                          Dskip + (size_t)l * DM);
        glu_kernel<<<dim3(2048), dim3(256), 0, stream>>>(Ag,
            Bt + (size_t)l * 131072, hg, hp, b_out + (size_t)l * 512);
        ln_kernel<<<dim3(16384), dim3(256), 0, stream>>>(hp, hg,
            ln_w + (size_t)l * DM, ln_b + (size_t)l * DM);
    }

    decode_kernel<<<dim3(16384), dim3(256), 0, stream>>>(hg, W_dec, b_dec,
                                                         (float*)d_out);
}

// Round 8
// 941.185 us; speedup vs baseline: 1.0412x; 1.0412x over previous
//
#include <hip/hip_runtime.h>
#include <math.h>

#define DM 256          // d_model
#define NS 64           // N state
#define SP 128          // spatial H == W
#define KPAD 32         // zero-pad rows in front of kernel (for negative indices)
#define KROWS (KPAD + SP)   // 160

typedef __attribute__((ext_vector_type(8))) short bf16x8;
typedef __attribute__((ext_vector_type(4))) float f32x4;
typedef __attribute__((ext_vector_type(2))) float f32x2;

__device__ __forceinline__ float gelu_f(float x) {
    float x3 = x * x * x;
    return 0.5f * x * (1.0f + tanhf(0.7978845608028654f * (x + 0.044715f * x3)));
}
__device__ __forceinline__ float sigmoid_f(float x) {
    return 1.0f / (1.0f + expf(-x));
}
__device__ __forceinline__ unsigned short f2bf(float f) {   // RNE f32->bf16
    unsigned u = __float_as_uint(f);
    u += 0x7fff + ((u >> 16) & 1);
    return (unsigned short)(u >> 16);
}
__device__ __forceinline__ float bf2f(unsigned short b) {
    return __uint_as_float(((unsigned)b) << 16);
}
// packed 2xfp32 FMA (halves instruction count vs scalar)
__device__ __forceinline__ f32x2 pkfma(f32x2 a, f32x2 b, f32x2 c) {
    f32x2 d;
    asm("v_pk_fma_f32 %0, %1, %2, %3" : "=v"(d) : "v"(a), "v"(b), "v"(c));
    return d;
}

// ---------------------------------------------------------------------------
// S4D kernel generation (verified r1-r5). K_Tp fp32 [la][KROWS][DM], rows
// [0,KPAD) zeroed by memset.
// ---------------------------------------------------------------------------
__global__ __launch_bounds__(128) void gen_k_kernel(
        const float* __restrict__ log_dt, const float* __restrict__ logA_re,
        const float* __restrict__ A_im,   const float* __restrict__ C_re,
        const float* __restrict__ C_im,   float* __restrict__ K_Tp) {
    int blk = blockIdx.x;
    int d  = blk & (DM - 1);
    int la = blk >> 8;
    int q  = threadIdx.x;
    __shared__ float s_cbr[NS], s_cbi[NS], s_dr[NS], s_di[NS];
    int pbase = (la * DM + d) * NS;
    float dt = expf(log_dt[la * DM + d]);
    if (q < NS) {
        int n = q;
        float ar = -expf(logA_re[pbase + n]);
        float ai = A_im[pbase + n];
        float dr = dt * ar, di = dt * ai;
        float er = expf(dr);
        float sn, cs;
        sincosf(di, &sn, &cs);
        float nr = er * cs - 1.0f, ni = er * sn;
        float inv = 1.0f / (ar * ar + ai * ai);
        float br = (nr * ar + ni * ai) * inv;
        float bi = (ni * ar - nr * ai) * inv;
        float cr = C_re[pbase + n], ci = C_im[pbase + n];
        s_cbr[n] = cr * br - ci * bi;
        s_cbi[n] = cr * bi + ci * br;
        s_dr[n] = dr;
        s_di[n] = di;
    }
    __syncthreads();
    float fq = (float)q;
    float acc = 0.0f;
    for (int n = 0; n < NS; ++n) {
        float pr = expf(s_dr[n] * fq);
        float sn, cs;
        sincosf(s_di[n] * fq, &sn, &cs);
        acc += s_cbr[n] * (pr * cs) - s_cbi[n] * (pr * sn);
    }
    K_Tp[(la * KROWS + KPAD + q) * DM + d] = 2.0f * acc;
}

// ---------------------------------------------------------------------------
// W_out fp32 [l][k=256][n=512]  ->  B_T bf16 [l][n=512][k=256]
// ---------------------------------------------------------------------------
__global__ __launch_bounds__(256) void prep_b_kernel(
        const float* __restrict__ Wo, unsigned short* __restrict__ Bt) {
    int idx = blockIdx.x * 256 + threadIdx.x;
    int l = idx >> 17, rem = idx & 131071, n = rem >> 8, k = rem & 255;
    Bt[idx] = f2bf(Wo[(size_t)l * 131072 + k * 512 + n]);
}

// ---------------------------------------------------------------------------
// Encoder -> bf16 h (pos-major), packed pair stores.
// ---------------------------------------------------------------------------
__global__ __launch_bounds__(256) void encode_kernel(
        const float* __restrict__ x, const float* __restrict__ g,
        const float* __restrict__ W_enc, const float* __restrict__ b_enc,
        unsigned short* __restrict__ h) {
    int total = 4 * SP * SP * 128;   // channel pairs
    for (int idx = blockIdx.x * blockDim.x + threadIdx.x; idx < total;
         idx += gridDim.x * blockDim.x) {
        int c = (idx & 127) * 2;
        int pos = idx >> 7;
        float xv = x[pos], gv = g[pos];
        float v0 = xv * W_enc[c] + gv * W_enc[DM + c] + b_enc[c];
        float v1 = xv * W_enc[c + 1] + gv * W_enc[DM + c + 1] + b_enc[c + 1];
        unsigned o = (unsigned)f2bf(v0) | ((unsigned)f2bf(v1) << 16);
        *(unsigned*)(h + (size_t)pos * DM + c) = o;
    }
}

// ---------------------------------------------------------------------------
// Causal conv (r5 math, latency fixed): input row staged in LDS (64KB), inner
// u-reads are conflict-free ds_read_b32; K taps 16-deep batched from L2.
// grid 1024 = row(512) x tile-pair(2): tp0 -> tiles {0,3}, tp1 -> {1,2}
// (balanced 5 j-blocks per block). Thread = (tile, channel-pair); ONE tile
// per thread so acc[32]+kreg[32]+kn2[16] fit the 256-VGPR cap at 2 waves/SIMD.
// MODE 0: in=h bf16 (b,hh,w,d) -> out T bf16 transposed (b,w,hh,d).
// MODE 1: in=T bf16 (b,w,hh,d) -> A=gelu(conv + h*Dskip) bf16, m=(b,w,hh).
// ---------------------------------------------------------------------------
template <int MODE>
__global__ __launch_bounds__(256, 2) void conv_kernel(
        const unsigned short* __restrict__ in, unsigned short* __restrict__ out,
        const float* __restrict__ KT, const unsigned short* __restrict__ h,
        const float* __restrict__ Dsk) {
    __shared__ unsigned short Urow[SP * DM];       // 64 KB raw row [j][ch]
    int bid = blockIdx.x;
    int r = bid >> 1, tp = bid & 1;
    int tid = threadIdx.x;
    int sel = tid >> 7, c2 = tid & 127;
    int c = c2 * 2;
    int b = r >> 7, rr = r & 127;

    {   // stage row (coalesced 16B/lane)
        const uint4* src = (const uint4*)(in + (size_t)r * (SP * DM));
        uint4* dst = (uint4*)Urow;
        #pragma unroll
        for (int it = 0; it < 16; ++it)
            dst[it * 256 + tid] = src[it * 256 + tid];
    }
    __syncthreads();

    f32x2 dk2 = (f32x2){0.f, 0.f};
    if (MODE == 1) { dk2[0] = Dsk[c]; dk2[1] = Dsk[c + 1]; }

    int t = tp ? (sel ? 2 : 1) : (sel ? 3 : 0);
    int w0 = t * 32;
    f32x2 acc[32], kreg[32];
    #pragma unroll
    for (int i = 0; i < 32; ++i) acc[i] = (f32x2){0.f, 0.f};
    const float* kbase = KT + (size_t)(KPAD + w0) * DM + c;
    #pragma unroll
    for (int s = 0; s < 32; ++s) kreg[s] = *(const f32x2*)(kbase + (size_t)s * DM);

    for (int jb = 0; jb <= t; ++jb) {
        const float* kb = KT + (size_t)(KPAD + w0 - jb * 32 - 1) * DM + c;
        #pragma unroll
        for (int hb = 0; hb < 2; ++hb) {
            f32x2 kn2[16];
            #pragma unroll
            for (int q = 0; q < 16; ++q)
                kn2[q] = *(const f32x2*)(kb - (size_t)(hb * 16 + q) * DM);
            #pragma unroll
            for (int jj2 = 0; jj2 < 16; ++jj2) {
                int jj = hb * 16 + jj2;
                int j = jb * 32 + jj;
                unsigned us = *(const unsigned*)(Urow + j * DM + c);   // LDS
                f32x2 u2;
                u2[0] = __uint_as_float(us << 16);
                u2[1] = __uint_as_float(us & 0xffff0000u);
                #pragma unroll
                for (int i = 0; i < 32; ++i)
                    acc[i] = pkfma(kreg[(i - jj) & 31], u2, acc[i]);
                kreg[(31 - jj) & 31] = kn2[jj2];
            }
        }
    }

    if (MODE == 0) {
        #pragma unroll
        for (int i = 0; i < 32; ++i) {
            unsigned o = (unsigned)f2bf(acc[i][0]) | ((unsigned)f2bf(acc[i][1]) << 16);
            *(unsigned*)(out + ((size_t)((b << 7) | (w0 + i)) * SP + rr) * DM + c) = o;
        }
    } else {
        #pragma unroll
        for (int i = 0; i < 32; ++i) {
            int hh = w0 + i;
            unsigned hu = *(const unsigned*)(h + ((size_t)((b << 14) | (hh << 7) | rr)) * DM + c);
            float v0 = gelu_f(fmaf(__uint_as_float(hu << 16), dk2[0], acc[i][0]));
            float v1 = gelu_f(fmaf(__uint_as_float(hu & 0xffff0000u), dk2[1], acc[i][1]));
            unsigned o = (unsigned)f2bf(v0) | ((unsigned)f2bf(v1) << 16);
            *(unsigned*)(out + ((size_t)r * SP + hh) * DM + c) = o;
        }
    }
}

// ---------------------------------------------------------------------------
// GLU GEMM, barrier-free & LDS-free (r5 verbatim, verified):
// hp = (A@W_a + b_a) * sigmoid(A@W_g + b_g) + h  (bf16, pos-order)
// 8 waves/block; wave wv holds persistent W frags for a-cols [wv*32,+32) AND
// g-cols [256+wv*32,+32). Operand-swapped MFMA; af software-pipelined.
// ---------------------------------------------------------------------------
__global__ __launch_bounds__(512, 1) void glu_kernel(
        const unsigned short* __restrict__ Ab, const unsigned short* __restrict__ Bt,
        const unsigned short* __restrict__ h, unsigned short* __restrict__ hp,
        const float* __restrict__ bo) {
    int tid = threadIdx.x;
    int lane = tid & 63, wv = tid >> 6;
    int lc = lane & 15, g = lane >> 4;
    int m0 = blockIdx.x * 128;

    bf16x8 wf[4][8];
    #pragma unroll
    for (int cf = 0; cf < 4; ++cf) {
        int colb = (cf < 2) ? (wv * 32 + cf * 16) : (256 + wv * 32 + (cf - 2) * 16);
        #pragma unroll
        for (int kk = 0; kk < 8; ++kk)
            wf[cf][kk] = *(const bf16x8*)(Bt + (size_t)(colb + lc) * DM + kk * 32 + g * 8);
    }
    float4 ba[2], bg[2];
    #pragma unroll
    for (int cf = 0; cf < 2; ++cf) {
        ba[cf] = *(const float4*)(bo + wv * 32 + cf * 16 + g * 4);
        bg[cf] = *(const float4*)(bo + 256 + wv * 32 + cf * 16 + g * 4);
    }

    bf16x8 af[8];
    #pragma unroll
    for (int kk = 0; kk < 8; ++kk)
        af[kk] = *(const bf16x8*)(Ab + (size_t)(m0 + lc) * DM + kk * 32 + g * 8);

    #pragma unroll
    for (int s = 0; s < 8; ++s) {
        int m = m0 + s * 16 + lc;
        int b_ = m >> 14, w_ = (m >> 7) & 127, hh_ = m & 127;
        size_t pbase = ((size_t)((b_ << 14) | (hh_ << 7) | w_)) * DM + wv * 32 + g * 4;
        uint2 hv0 = *(const uint2*)(h + pbase);
        uint2 hv1 = *(const uint2*)(h + pbase + 16);

        f32x4 acc0 = (f32x4){0.f, 0.f, 0.f, 0.f};
        f32x4 acc1 = acc0, acc2 = acc0, acc3 = acc0;
        #pragma unroll
        for (int kk = 0; kk < 8; ++kk) {
            acc0 = __builtin_amdgcn_mfma_f32_16x16x32_bf16(wf[0][kk], af[kk], acc0, 0, 0, 0);
            acc1 = __builtin_amdgcn_mfma_f32_16x16x32_bf16(wf[1][kk], af[kk], acc1, 0, 0, 0);
            acc2 = __builtin_amdgcn_mfma_f32_16x16x32_bf16(wf[2][kk], af[kk], acc2, 0, 0, 0);
            acc3 = __builtin_amdgcn_mfma_f32_16x16x32_bf16(wf[3][kk], af[kk], acc3, 0, 0, 0);
            if (s < 7)
                af[kk] = *(const bf16x8*)(Ab + (size_t)(m0 + (s + 1) * 16 + lc) * DM + kk * 32 + g * 8);
        }

        float hr0[4], hr1[4];
        hr0[0] = __uint_as_float(hv0.x << 16);
        hr0[1] = __uint_as_float(hv0.x & 0xffff0000u);
        hr0[2] = __uint_as_float(hv0.y << 16);
        hr0[3] = __uint_as_float(hv0.y & 0xffff0000u);
        hr1[0] = __uint_as_float(hv1.x << 16);
        hr1[1] = __uint_as_float(hv1.x & 0xffff0000u);
        hr1[2] = __uint_as_float(hv1.y << 16);
        hr1[3] = __uint_as_float(hv1.y & 0xffff0000u);
        float o0[4], o1[4];
        #pragma unroll
        for (int reg = 0; reg < 4; ++reg) {
            o0[reg] = (acc0[reg] + (&ba[0].x)[reg]) * sigmoid_f(acc2[reg] + (&bg[0].x)[reg]) + hr0[reg];
            o1[reg] = (acc1[reg] + (&ba[1].x)[reg]) * sigmoid_f(acc3[reg] + (&bg[1].x)[reg]) + hr1[reg];
        }
        uint2 ov0, ov1;
        ov0.x = (unsigned)f2bf(o0[0]) | ((unsigned)f2bf(o0[1]) << 16);
        ov0.y = (unsigned)f2bf(o0[2]) | ((unsigned)f2bf(o0[3]) << 16);
        ov1.x = (unsigned)f2bf(o1[0]) | ((unsigned)f2bf(o1[1]) << 16);
        ov1.y = (unsigned)f2bf(o1[2]) | ((unsigned)f2bf(o1[3]) << 16);
        *(uint2*)(hp + pbase) = ov0;
        *(uint2*)(hp + pbase + 16) = ov1;
    }
}

// ---------------------------------------------------------------------------
// LayerNorm: h = LN(hp) (bf16 -> bf16, pos-order). Wave = 1 row, lane = 4 ch.
// ---------------------------------------------------------------------------
__global__ __launch_bounds__(256) void ln_kernel(
        const unsigned short* __restrict__ hp, unsigned short* __restrict__ h,
        const float* __restrict__ lnw, const float* __restrict__ lnb) {
    int pos = blockIdx.x * 4 + (threadIdx.x >> 6);
    int lane = threadIdx.x & 63;
    size_t base = (size_t)pos * DM + lane * 4;
    uint2 hv = *(const uint2*)(hp + base);
    float v[4];
    v[0] = __uint_as_float(hv.x << 16);
    v[1] = __uint_as_float(hv.x & 0xffff0000u);
    v[2] = __uint_as_float(hv.y << 16);
    v[3] = __uint_as_float(hv.y & 0xffff0000u);
    float s1 = v[0] + v[1] + v[2] + v[3];
    float s2 = v[0] * v[0] + v[1] * v[1] + v[2] * v[2] + v[3] * v[3];
    #pragma unroll
    for (int off = 1; off < 64; off <<= 1) {
        s1 += __shfl_xor(s1, off);
        s2 += __shfl_xor(s2, off);
    }
    float mean = s1 * (1.0f / 256.0f);
    float var = s2 * (1.0f / 256.0f) - mean * mean;
    float inv = rsqrtf(var + 1e-5f);
    float4 w4 = *(const float4*)(lnw + lane * 4);
    float4 b4 = *(const float4*)(lnb + lane * 4);
    float o0 = (v[0] - mean) * inv * w4.x + b4.x;
    float o1 = (v[1] - mean) * inv * w4.y + b4.y;
    float o2 = (v[2] - mean) * inv * w4.z + b4.z;
    float o3 = (v[3] - mean) * inv * w4.w + b4.w;
    uint2 ov;
    ov.x = (unsigned)f2bf(o0) | ((unsigned)f2bf(o1) << 16);
    ov.y = (unsigned)f2bf(o2) | ((unsigned)f2bf(o3) << 16);
    *(uint2*)(h + base) = ov;
}

// ---------------------------------------------------------------------------
// Decoder: bf16 h in.
// ---------------------------------------------------------------------------
__global__ __launch_bounds__(256) void decode_kernel(
        const unsigned short* __restrict__ h, const float* __restrict__ Wd,
        const float* __restrict__ bd, float* __restrict__ out) {
    int pos = blockIdx.x * 4 + (threadIdx.x >> 6);
    int lane = threadIdx.x & 63;
    float s = 0.0f;
    #pragma unroll
    for (int j = 0; j < 4; ++j) {
        int d = j * 64 + lane;
        s += bf2f(h[(size_t)pos * DM + d]) * Wd[d];
    }
    #pragma unroll
    for (int off = 32; off > 0; off >>= 1) s += __shfl_down(s, off);
    if (lane == 0) out[pos] = s + bd[0];
}

// ---------------------------------------------------------------------------
extern "C" void kernel_launch(void* const* d_in, const int* in_sizes, int n_in,
                              void* d_out, int out_size, void* d_ws, size_t ws_size,
                              hipStream_t stream) {
    const float* x       = (const float*)d_in[0];
    const float* grid    = (const float*)d_in[1];
    const float* W_enc   = (const float*)d_in[2];
    const float* b_enc   = (const float*)d_in[3];
    const float* log_dt  = (const float*)d_in[4];
    const float* logA_re = (const float*)d_in[5];
    const float* A_im    = (const float*)d_in[6];
    const float* C_re    = (const float*)d_in[7];
    const float* C_im    = (const float*)d_in[8];
    const float* Dskip   = (const float*)d_in[9];
    const float* W_out   = (const float*)d_in[10];
    const float* b_out   = (const float*)d_in[11];
    const float* ln_w    = (const float*)d_in[12];
    const float* ln_b    = (const float*)d_in[13];
    const float* W_dec   = (const float*)d_in[14];
    const float* b_dec   = (const float*)d_in[15];

    char* base = (char*)d_ws;
    float*          K_Tp = (float*)base;                              // 1,310,720 B
    unsigned short* hbuf = (unsigned short*)(base + 1310720);         // 33,554,432 B
    unsigned short* T16  = (unsigned short*)(base + 34865152);        // 33,554,432 B
    unsigned short* Abuf = (unsigned short*)(base + 68419584);        // 33,554,432 B
    unsigned short* Bt   = (unsigned short*)(base + 101974016);       // 1,048,576 B
    unsigned short* hp   = T16;    // reuse: T16 dead after conv_h

    hipMemsetAsync(K_Tp, 0, (size_t)8 * KROWS * DM * sizeof(float), stream);
    gen_k_kernel<<<dim3(8 * DM), dim3(128), 0, stream>>>(log_dt, logA_re, A_im,
                                                         C_re, C_im, K_Tp);
    prep_b_kernel<<<dim3(2048), dim3(256), 0, stream>>>(W_out, Bt);
    encode_kernel<<<dim3(2048), dim3(256), 0, stream>>>(x, grid, W_enc, b_enc, hbuf);

    for (int l = 0; l < 4; ++l) {
        const float* Kh = K_Tp + (size_t)(l * 2 + 0) * KROWS * DM;
        const float* Kw = K_Tp + (size_t)(l * 2 + 1) * KROWS * DM;
        conv_kernel<0><<<dim3(1024), dim3(256), 0, stream>>>(hbuf, T16, Kw,
                                                             (const unsigned short*)nullptr, (const float*)nullptr);
        conv_kernel<1><<<dim3(1024), dim3(256), 0, stream>>>(T16, Abuf, Kh,
                                                             hbuf, Dskip + (size_t)l * DM);
        glu_kernel<<<dim3(512), dim3(512), 0, stream>>>(Abuf,
            Bt + (size_t)l * 131072, hbuf, hp, b_out + (size_t)l * 512);
        ln_kernel<<<dim3(16384), dim3(256), 0, stream>>>(hp, hbuf,
            ln_w + (size_t)l * DM, ln_b + (size_t)l * DM);
    }

    decode_kernel<<<dim3(16384), dim3(256), 0, stream>>>(hbuf, W_dec, b_dec,
                                                         (float*)d_out);
}

// Round 9
// 855.994 us; speedup vs baseline: 1.1448x; 1.0995x over previous
//
#include <hip/hip_runtime.h>
#include <math.h>

#define DM 256          // d_model
#define NS 64           // N state
#define SP 128          // spatial H == W
#define KPAD 32         // zero-pad rows in front of kernel (for negative indices)
#define KROWS (KPAD + SP)   // 160

typedef __attribute__((ext_vector_type(8))) short bf16x8;
typedef __attribute__((ext_vector_type(4))) float f32x4;
typedef __attribute__((ext_vector_type(2))) float f32x2;

__device__ __forceinline__ float gelu_f(float x) {
    float x3 = x * x * x;
    return 0.5f * x * (1.0f + tanhf(0.7978845608028654f * (x + 0.044715f * x3)));
}
__device__ __forceinline__ float sigmoid_f(float x) {
    return 1.0f / (1.0f + expf(-x));
}
__device__ __forceinline__ unsigned short f2bf(float f) {   // RNE f32->bf16
    unsigned u = __float_as_uint(f);
    u += 0x7fff + ((u >> 16) & 1);
    return (unsigned short)(u >> 16);
}
__device__ __forceinline__ float bf2f(unsigned short b) {
    return __uint_as_float(((unsigned)b) << 16);
}
// packed 2xfp32 FMA (halves instruction count vs scalar)
__device__ __forceinline__ f32x2 pkfma(f32x2 a, f32x2 b, f32x2 c) {
    f32x2 d;
    asm("v_pk_fma_f32 %0, %1, %2, %3" : "=v"(d) : "v"(a), "v"(b), "v"(c));
    return d;
}

// ---------------------------------------------------------------------------
// S4D kernel generation (verified r1-r8). K_Tp fp32 [la][KROWS][DM], rows
// [0,KPAD) zeroed by memset.
// ---------------------------------------------------------------------------
__global__ __launch_bounds__(128) void gen_k_kernel(
        const float* __restrict__ log_dt, const float* __restrict__ logA_re,
        const float* __restrict__ A_im,   const float* __restrict__ C_re,
        const float* __restrict__ C_im,   float* __restrict__ K_Tp) {
    int blk = blockIdx.x;
    int d  = blk & (DM - 1);
    int la = blk >> 8;
    int q  = threadIdx.x;
    __shared__ float s_cbr[NS], s_cbi[NS], s_dr[NS], s_di[NS];
    int pbase = (la * DM + d) * NS;
    float dt = expf(log_dt[la * DM + d]);
    if (q < NS) {
        int n = q;
        float ar = -expf(logA_re[pbase + n]);
        float ai = A_im[pbase + n];
        float dr = dt * ar, di = dt * ai;
        float er = expf(dr);
        float sn, cs;
        sincosf(di, &sn, &cs);
        float nr = er * cs - 1.0f, ni = er * sn;
        float inv = 1.0f / (ar * ar + ai * ai);
        float br = (nr * ar + ni * ai) * inv;
        float bi = (ni * ar - nr * ai) * inv;
        float cr = C_re[pbase + n], ci = C_im[pbase + n];
        s_cbr[n] = cr * br - ci * bi;
        s_cbi[n] = cr * bi + ci * br;
        s_dr[n] = dr;
        s_di[n] = di;
    }
    __syncthreads();
    float fq = (float)q;
    float acc = 0.0f;
    for (int n = 0; n < NS; ++n) {
        float pr = expf(s_dr[n] * fq);
        float sn, cs;
        sincosf(s_di[n] * fq, &sn, &cs);
        acc += s_cbr[n] * (pr * cs) - s_cbi[n] * (pr * sn);
    }
    K_Tp[(la * KROWS + KPAD + q) * DM + d] = 2.0f * acc;
}

// ---------------------------------------------------------------------------
// W_out fp32 [l][k=256][n=512]  ->  B_T bf16 [l][n=512][k=256]
// ---------------------------------------------------------------------------
__global__ __launch_bounds__(256) void prep_b_kernel(
        const float* __restrict__ Wo, unsigned short* __restrict__ Bt) {
    int idx = blockIdx.x * 256 + threadIdx.x;
    int l = idx >> 17, rem = idx & 131071, n = rem >> 8, k = rem & 255;
    Bt[idx] = f2bf(Wo[(size_t)l * 131072 + k * 512 + n]);
}

// ---------------------------------------------------------------------------
// Encoder -> bf16 h (pos-major), packed pair stores.
// ---------------------------------------------------------------------------
__global__ __launch_bounds__(256) void encode_kernel(
        const float* __restrict__ x, const float* __restrict__ g,
        const float* __restrict__ W_enc, const float* __restrict__ b_enc,
        unsigned short* __restrict__ h) {
    int total = 4 * SP * SP * 128;   // channel pairs
    for (int idx = blockIdx.x * blockDim.x + threadIdx.x; idx < total;
         idx += gridDim.x * blockDim.x) {
        int c = (idx & 127) * 2;
        int pos = idx >> 7;
        float xv = x[pos], gv = g[pos];
        float v0 = xv * W_enc[c] + gv * W_enc[DM + c] + b_enc[c];
        float v1 = xv * W_enc[c + 1] + gv * W_enc[DM + c + 1] + b_enc[c + 1];
        unsigned o = (unsigned)f2bf(v0) | ((unsigned)f2bf(v1) << 16);
        *(unsigned*)(h + (size_t)pos * DM + c) = o;
    }
}

// ---------------------------------------------------------------------------
// Causal conv, 16-output tiles sized to the register budget:
// acc[16]+kreg[16] (f32x2) + kn2[8] ~= 96 VGPR -> fits 128-cap at 4 waves/SIMD
// (__launch_bounds__(256,4)), no spill, no LDS. Direct coalesced global
// u-reads (L2/L3-hot). Grid = 512 rows x 4 tile-pairs {t,7-t}; block halves
// are wave-uniform. Ring of 16 kernel taps, kn 8-deep batched.
// MODE 0: in=h bf16 (b,hh,w,d) -> out T bf16 transposed (b,w,hh,d).
// MODE 1: in=T bf16 (b,w,hh,d) -> A=gelu(conv + h*Dskip) bf16, m=(b,w,hh).
// ---------------------------------------------------------------------------
template <int MODE>
__global__ __launch_bounds__(256, 4) void conv_kernel(
        const unsigned short* __restrict__ in, unsigned short* __restrict__ out,
        const float* __restrict__ KT, const unsigned short* __restrict__ h,
        const float* __restrict__ Dsk) {
    int bid = blockIdx.x;
    int r = bid >> 2, pr = bid & 3;            // row, pair index
    int tid = threadIdx.x;
    int half = tid >> 7, c2 = tid & 127;
    int c = c2 * 2;
    int t = half ? (7 - pr) : pr;              // tile 0..7 (16 outputs)
    int w0 = t * 16;
    const unsigned short* row = in + (size_t)r * (SP * DM) + c;
    int b = r >> 7, rr = r & 127;

    f32x2 dk2 = (f32x2){0.f, 0.f};
    if (MODE == 1) { dk2[0] = Dsk[c]; dk2[1] = Dsk[c + 1]; }

    f32x2 acc[16], kreg[16];
    #pragma unroll
    for (int i = 0; i < 16; ++i) acc[i] = (f32x2){0.f, 0.f};
    const float* kbase = KT + (size_t)(KPAD + w0) * DM + c;
    #pragma unroll
    for (int s = 0; s < 16; ++s) kreg[s] = *(const f32x2*)(kbase + (size_t)s * DM);

    for (int jb = 0; jb <= t; ++jb) {
        const float* kb = KT + (size_t)(KPAD + w0 - jb * 16 - 1) * DM + c;
        const unsigned short* ub = row + (size_t)jb * 16 * DM;
        #pragma unroll
        for (int hb = 0; hb < 2; ++hb) {
            f32x2 kn2[8];
            #pragma unroll
            for (int q = 0; q < 8; ++q)
                kn2[q] = *(const f32x2*)(kb - (size_t)(hb * 8 + q) * DM);
            #pragma unroll
            for (int jj2 = 0; jj2 < 8; ++jj2) {
                int jj = hb * 8 + jj2;
                unsigned us = *(const unsigned*)(ub + (size_t)jj * DM);
                f32x2 u2;
                u2[0] = __uint_as_float(us << 16);
                u2[1] = __uint_as_float(us & 0xffff0000u);
                #pragma unroll
                for (int i = 0; i < 16; ++i)
                    acc[i] = pkfma(kreg[(i - jj) & 15], u2, acc[i]);
                kreg[(15 - jj) & 15] = kn2[jj2];
            }
        }
    }

    if (MODE == 0) {
        #pragma unroll
        for (int i = 0; i < 16; ++i) {
            unsigned o = (unsigned)f2bf(acc[i][0]) | ((unsigned)f2bf(acc[i][1]) << 16);
            *(unsigned*)(out + ((size_t)((b << 7) | (w0 + i)) * SP + rr) * DM + c) = o;
        }
    } else {
        #pragma unroll
        for (int i = 0; i < 16; ++i) {
            int hh = w0 + i;
            unsigned hu = *(const unsigned*)(h + ((size_t)((b << 14) | (hh << 7) | rr)) * DM + c);
            float v0 = gelu_f(fmaf(__uint_as_float(hu << 16), dk2[0], acc[i][0]));
            float v1 = gelu_f(fmaf(__uint_as_float(hu & 0xffff0000u), dk2[1], acc[i][1]));
            unsigned o = (unsigned)f2bf(v0) | ((unsigned)f2bf(v1) << 16);
            *(unsigned*)(out + ((size_t)r * SP + hh) * DM + c) = o;
        }
    }
}

// ---------------------------------------------------------------------------
// GLU GEMM, barrier-free & LDS-free (r5 verbatim, verified):
// hp = (A@W_a + b_a) * sigmoid(A@W_g + b_g) + h  (bf16, pos-order)
// 8 waves/block; wave wv holds persistent W frags for a-cols [wv*32,+32) AND
// g-cols [256+wv*32,+32). Operand-swapped MFMA; af software-pipelined.
// ---------------------------------------------------------------------------
__global__ __launch_bounds__(512, 1) void glu_kernel(
        const unsigned short* __restrict__ Ab, const unsigned short* __restrict__ Bt,
        const unsigned short* __restrict__ h, unsigned short* __restrict__ hp,
        const float* __restrict__ bo) {
    int tid = threadIdx.x;
    int lane = tid & 63, wv = tid >> 6;
    int lc = lane & 15, g = lane >> 4;
    int m0 = blockIdx.x * 128;

    bf16x8 wf[4][8];
    #pragma unroll
    for (int cf = 0; cf < 4; ++cf) {
        int colb = (cf < 2) ? (wv * 32 + cf * 16) : (256 + wv * 32 + (cf - 2) * 16);
        #pragma unroll
        for (int kk = 0; kk < 8; ++kk)
            wf[cf][kk] = *(const bf16x8*)(Bt + (size_t)(colb + lc) * DM + kk * 32 + g * 8);
    }
    float4 ba[2], bg[2];
    #pragma unroll
    for (int cf = 0; cf < 2; ++cf) {
        ba[cf] = *(const float4*)(bo + wv * 32 + cf * 16 + g * 4);
        bg[cf] = *(const float4*)(bo + 256 + wv * 32 + cf * 16 + g * 4);
    }

    bf16x8 af[8];
    #pragma unroll
    for (int kk = 0; kk < 8; ++kk)
        af[kk] = *(const bf16x8*)(Ab + (size_t)(m0 + lc) * DM + kk * 32 + g * 8);

    #pragma unroll
    for (int s = 0; s < 8; ++s) {
        int m = m0 + s * 16 + lc;
        int b_ = m >> 14, w_ = (m >> 7) & 127, hh_ = m & 127;
        size_t pbase = ((size_t)((b_ << 14) | (hh_ << 7) | w_)) * DM + wv * 32 + g * 4;
        uint2 hv0 = *(const uint2*)(h + pbase);
        uint2 hv1 = *(const uint2*)(h + pbase + 16);

        f32x4 acc0 = (f32x4){0.f, 0.f, 0.f, 0.f};
        f32x4 acc1 = acc0, acc2 = acc0, acc3 = acc0;
        #pragma unroll
        for (int kk = 0; kk < 8; ++kk) {
            acc0 = __builtin_amdgcn_mfma_f32_16x16x32_bf16(wf[0][kk], af[kk], acc0, 0, 0, 0);
            acc1 = __builtin_amdgcn_mfma_f32_16x16x32_bf16(wf[1][kk], af[kk], acc1, 0, 0, 0);
            acc2 = __builtin_amdgcn_mfma_f32_16x16x32_bf16(wf[2][kk], af[kk], acc2, 0, 0, 0);
            acc3 = __builtin_amdgcn_mfma_f32_16x16x32_bf16(wf[3][kk], af[kk], acc3, 0, 0, 0);
            if (s < 7)
                af[kk] = *(const bf16x8*)(Ab + (size_t)(m0 + (s + 1) * 16 + lc) * DM + kk * 32 + g * 8);
        }

        float hr0[4], hr1[4];
        hr0[0] = __uint_as_float(hv0.x << 16);
        hr0[1] = __uint_as_float(hv0.x & 0xffff0000u);
        hr0[2] = __uint_as_float(hv0.y << 16);
        hr0[3] = __uint_as_float(hv0.y & 0xffff0000u);
        hr1[0] = __uint_as_float(hv1.x << 16);
        hr1[1] = __uint_as_float(hv1.x & 0xffff0000u);
        hr1[2] = __uint_as_float(hv1.y << 16);
        hr1[3] = __uint_as_float(hv1.y & 0xffff0000u);
        float o0[4], o1[4];
        #pragma unroll
        for (int reg = 0; reg < 4; ++reg) {
            o0[reg] = (acc0[reg] + (&ba[0].x)[reg]) * sigmoid_f(acc2[reg] + (&bg[0].x)[reg]) + hr0[reg];
            o1[reg] = (acc1[reg] + (&ba[1].x)[reg]) * sigmoid_f(acc3[reg] + (&bg[1].x)[reg]) + hr1[reg];
        }
        uint2 ov0, ov1;
        ov0.x = (unsigned)f2bf(o0[0]) | ((unsigned)f2bf(o0[1]) << 16);
        ov0.y = (unsigned)f2bf(o0[2]) | ((unsigned)f2bf(o0[3]) << 16);
        ov1.x = (unsigned)f2bf(o1[0]) | ((unsigned)f2bf(o1[1]) << 16);
        ov1.y = (unsigned)f2bf(o1[2]) | ((unsigned)f2bf(o1[3]) << 16);
        *(uint2*)(hp + pbase) = ov0;
        *(uint2*)(hp + pbase + 16) = ov1;
    }
}

// ---------------------------------------------------------------------------
// LayerNorm: h = LN(hp) (bf16 -> bf16, pos-order). Wave = 1 row, lane = 4 ch.
// ---------------------------------------------------------------------------
__global__ __launch_bounds__(256) void ln_kernel(
        const unsigned short* __restrict__ hp, unsigned short* __restrict__ h,
        const float* __restrict__ lnw, const float* __restrict__ lnb) {
    int pos = blockIdx.x * 4 + (threadIdx.x >> 6);
    int lane = threadIdx.x & 63;
    size_t base = (size_t)pos * DM + lane * 4;
    uint2 hv = *(const uint2*)(hp + base);
    float v[4];
    v[0] = __uint_as_float(hv.x << 16);
    v[1] = __uint_as_float(hv.x & 0xffff0000u);
    v[2] = __uint_as_float(hv.y << 16);
    v[3] = __uint_as_float(hv.y & 0xffff0000u);
    float s1 = v[0] + v[1] + v[2] + v[3];
    float s2 = v[0] * v[0] + v[1] * v[1] + v[2] * v[2] + v[3] * v[3];
    #pragma unroll
    for (int off = 1; off < 64; off <<= 1) {
        s1 += __shfl_xor(s1, off);
        s2 += __shfl_xor(s2, off);
    }
    float mean = s1 * (1.0f / 256.0f);
    float var = s2 * (1.0f / 256.0f) - mean * mean;
    float inv = rsqrtf(var + 1e-5f);
    float4 w4 = *(const float4*)(lnw + lane * 4);
    float4 b4 = *(const float4*)(lnb + lane * 4);
    float o0 = (v[0] - mean) * inv * w4.x + b4.x;
    float o1 = (v[1] - mean) * inv * w4.y + b4.y;
    float o2 = (v[2] - mean) * inv * w4.z + b4.z;
    float o3 = (v[3] - mean) * inv * w4.w + b4.w;
    uint2 ov;
    ov.x = (unsigned)f2bf(o0) | ((unsigned)f2bf(o1) << 16);
    ov.y = (unsigned)f2bf(o2) | ((unsigned)f2bf(o3) << 16);
    *(uint2*)(h + base) = ov;
}

// ---------------------------------------------------------------------------
// Decoder: bf16 h in.
// ---------------------------------------------------------------------------
__global__ __launch_bounds__(256) void decode_kernel(
        const unsigned short* __restrict__ h, const float* __restrict__ Wd,
        const float* __restrict__ bd, float* __restrict__ out) {
    int pos = blockIdx.x * 4 + (threadIdx.x >> 6);
    int lane = threadIdx.x & 63;
    float s = 0.0f;
    #pragma unroll
    for (int j = 0; j < 4; ++j) {
        int d = j * 64 + lane;
        s += bf2f(h[(size_t)pos * DM + d]) * Wd[d];
    }
    #pragma unroll
    for (int off = 32; off > 0; off >>= 1) s += __shfl_down(s, off);
    if (lane == 0) out[pos] = s + bd[0];
}

// ---------------------------------------------------------------------------
extern "C" void kernel_launch(void* const* d_in, const int* in_sizes, int n_in,
                              void* d_out, int out_size, void* d_ws, size_t ws_size,
                              hipStream_t stream) {
    const float* x       = (const float*)d_in[0];
    const float* grid    = (const float*)d_in[1];
    const float* W_enc   = (const float*)d_in[2];
    const float* b_enc   = (const float*)d_in[3];
    const float* log_dt  = (const float*)d_in[4];
    const float* logA_re = (const float*)d_in[5];
    const float* A_im    = (const float*)d_in[6];
    const float* C_re    = (const float*)d_in[7];
    const float* C_im    = (const float*)d_in[8];
    const float* Dskip   = (const float*)d_in[9];
    const float* W_out   = (const float*)d_in[10];
    const float* b_out   = (const float*)d_in[11];
    const float* ln_w    = (const float*)d_in[12];
    const float* ln_b    = (const float*)d_in[13];
    const float* W_dec   = (const float*)d_in[14];
    const float* b_dec   = (const float*)d_in[15];

    char* base = (char*)d_ws;
    float*          K_Tp = (float*)base;                              // 1,310,720 B
    unsigned short* hbuf = (unsigned short*)(base + 1310720);         // 33,554,432 B
    unsigned short* T16  = (unsigned short*)(base + 34865152);        // 33,554,432 B
    unsigned short* Abuf = (unsigned short*)(base + 68419584);        // 33,554,432 B
    unsigned short* Bt   = (unsigned short*)(base + 101974016);       // 1,048,576 B
    unsigned short* hp   = T16;    // reuse: T16 dead after conv_h

    hipMemsetAsync(K_Tp, 0, (size_t)8 * KROWS * DM * sizeof(float), stream);
    gen_k_kernel<<<dim3(8 * DM), dim3(128), 0, stream>>>(log_dt, logA_re, A_im,
                                                         C_re, C_im, K_Tp);
    prep_b_kernel<<<dim3(2048), dim3(256), 0, stream>>>(W_out, Bt);
    encode_kernel<<<dim3(2048), dim3(256), 0, stream>>>(x, grid, W_enc, b_enc, hbuf);

    for (int l = 0; l < 4; ++l) {
        const float* Kh = K_Tp + (size_t)(l * 2 + 0) * KROWS * DM;
        const float* Kw = K_Tp + (size_t)(l * 2 + 1) * KROWS * DM;
        conv_kernel<0><<<dim3(2048), dim3(256), 0, stream>>>(hbuf, T16, Kw,
                                                             (const unsigned short*)nullptr, (const float*)nullptr);
        conv_kernel<1><<<dim3(2048), dim3(256), 0, stream>>>(T16, Abuf, Kh,
                                                             hbuf, Dskip + (size_t)l * DM);
        glu_kernel<<<dim3(512), dim3(512), 0, stream>>>(Abuf,
            Bt + (size_t)l * 131072, hbuf, hp, b_out + (size_t)l * 512);
        ln_kernel<<<dim3(16384), dim3(256), 0, stream>>>(hp, hbuf,
            ln_w + (size_t)l * DM, ln_b + (size_t)l * DM);
    }

    decode_kernel<<<dim3(16384), dim3(256), 0, stream>>>(hbuf, W_dec, b_dec,
                                                         (float*)d_out);
}

// Round 10
// 834.359 us; speedup vs baseline: 1.1745x; 1.0259x over previous
//
#include <hip/hip_runtime.h>
#include <math.h>

#define DM 256          // d_model
#define NS 64           // N state
#define SP 128          // spatial H == W
#define KPAD 32         // zero-pad rows in front of kernel (for negative indices)
#define KROWS (KPAD + SP)   // 160

typedef __attribute__((ext_vector_type(8))) short bf16x8;
typedef __attribute__((ext_vector_type(4))) float f32x4;
typedef __attribute__((ext_vector_type(2))) float f32x2;

__device__ __forceinline__ float gelu_f(float x) {
    float x3 = x * x * x;
    return 0.5f * x * (1.0f + tanhf(0.7978845608028654f * (x + 0.044715f * x3)));
}
__device__ __forceinline__ float sigmoid_f(float x) {
    return 1.0f / (1.0f + expf(-x));
}
__device__ __forceinline__ unsigned short f2bf(float f) {   // RNE f32->bf16
    unsigned u = __float_as_uint(f);
    u += 0x7fff + ((u >> 16) & 1);
    return (unsigned short)(u >> 16);
}
__device__ __forceinline__ float bf2f(unsigned short b) {
    return __uint_as_float(((unsigned)b) << 16);
}
// packed 2xfp32 FMA (halves instruction count vs scalar)
__device__ __forceinline__ f32x2 pkfma(f32x2 a, f32x2 b, f32x2 c) {
    f32x2 d;
    asm("v_pk_fma_f32 %0, %1, %2, %3" : "=v"(d) : "v"(a), "v"(b), "v"(c));
    return d;
}

// ---------------------------------------------------------------------------
// S4D kernel generation (verified r1-r9). K_Tp fp32 [la][KROWS][DM], rows
// [0,KPAD) zeroed by memset.
// ---------------------------------------------------------------------------
__global__ __launch_bounds__(128) void gen_k_kernel(
        const float* __restrict__ log_dt, const float* __restrict__ logA_re,
        const float* __restrict__ A_im,   const float* __restrict__ C_re,
        const float* __restrict__ C_im,   float* __restrict__ K_Tp) {
    int blk = blockIdx.x;
    int d  = blk & (DM - 1);
    int la = blk >> 8;
    int q  = threadIdx.x;
    __shared__ float s_cbr[NS], s_cbi[NS], s_dr[NS], s_di[NS];
    int pbase = (la * DM + d) * NS;
    float dt = expf(log_dt[la * DM + d]);
    if (q < NS) {
        int n = q;
        float ar = -expf(logA_re[pbase + n]);
        float ai = A_im[pbase + n];
        float dr = dt * ar, di = dt * ai;
        float er = expf(dr);
        float sn, cs;
        sincosf(di, &sn, &cs);
        float nr = er * cs - 1.0f, ni = er * sn;
        float inv = 1.0f / (ar * ar + ai * ai);
        float br = (nr * ar + ni * ai) * inv;
        float bi = (ni * ar - nr * ai) * inv;
        float cr = C_re[pbase + n], ci = C_im[pbase + n];
        s_cbr[n] = cr * br - ci * bi;
        s_cbi[n] = cr * bi + ci * br;
        s_dr[n] = dr;
        s_di[n] = di;
    }
    __syncthreads();
    float fq = (float)q;
    float acc = 0.0f;
    for (int n = 0; n < NS; ++n) {
        float pr = expf(s_dr[n] * fq);
        float sn, cs;
        sincosf(s_di[n] * fq, &sn, &cs);
        acc += s_cbr[n] * (pr * cs) - s_cbi[n] * (pr * sn);
    }
    K_Tp[(la * KROWS + KPAD + q) * DM + d] = 2.0f * acc;
}

// ---------------------------------------------------------------------------
// W_out fp32 [l][k=256][n=512]  ->  B_T bf16 [l][n=512][k=256]
// ---------------------------------------------------------------------------
__global__ __launch_bounds__(256) void prep_b_kernel(
        const float* __restrict__ Wo, unsigned short* __restrict__ Bt) {
    int idx = blockIdx.x * 256 + threadIdx.x;
    int l = idx >> 17, rem = idx & 131071, n = rem >> 8, k = rem & 255;
    Bt[idx] = f2bf(Wo[(size_t)l * 131072 + k * 512 + n]);
}

// ---------------------------------------------------------------------------
// Encoder -> bf16 h (pos-major), packed pair stores.
// ---------------------------------------------------------------------------
__global__ __launch_bounds__(256) void encode_kernel(
        const float* __restrict__ x, const float* __restrict__ g,
        const float* __restrict__ W_enc, const float* __restrict__ b_enc,
        unsigned short* __restrict__ h) {
    int total = 4 * SP * SP * 128;   // channel pairs
    for (int idx = blockIdx.x * blockDim.x + threadIdx.x; idx < total;
         idx += gridDim.x * blockDim.x) {
        int c = (idx & 127) * 2;
        int pos = idx >> 7;
        float xv = x[pos], gv = g[pos];
        float v0 = xv * W_enc[c] + gv * W_enc[DM + c] + b_enc[c];
        float v1 = xv * W_enc[c + 1] + gv * W_enc[DM + c + 1] + b_enc[c + 1];
        unsigned o = (unsigned)f2bf(v0) | ((unsigned)f2bf(v1) << 16);
        *(unsigned*)(h + (size_t)pos * DM + c) = o;
    }
}

// ---------------------------------------------------------------------------
// Causal conv, 16-output tiles (r9 math, verified). NEW: u-loads batched
// 8-deep alongside the 8 k-tap loads -> 16 outstanding loads per hb burst,
// then 128 pk_fma with zero dependent-load stalls.
// acc[16]+kreg[16]+kn2[8]+us8[8] ~= 105 VGPR -> fits 128-cap @ 4 waves/SIMD.
// Grid = 512 rows x 4 tile-pairs {t,7-t}; block halves are wave-uniform.
// MODE 0: in=h bf16 (b,hh,w,d) -> out T bf16 transposed (b,w,hh,d).
// MODE 1: in=T bf16 (b,w,hh,d) -> A=gelu(conv + h*Dskip) bf16, m=(b,w,hh).
// ---------------------------------------------------------------------------
template <int MODE>
__global__ __launch_bounds__(256, 4) void conv_kernel(
        const unsigned short* __restrict__ in, unsigned short* __restrict__ out,
        const float* __restrict__ KT, const unsigned short* __restrict__ h,
        const float* __restrict__ Dsk) {
    int bid = blockIdx.x;
    int r = bid >> 2, pr = bid & 3;            // row, pair index
    int tid = threadIdx.x;
    int half = tid >> 7, c2 = tid & 127;
    int c = c2 * 2;
    int t = half ? (7 - pr) : pr;              // tile 0..7 (16 outputs)
    int w0 = t * 16;
    const unsigned short* row = in + (size_t)r * (SP * DM) + c;
    int b = r >> 7, rr = r & 127;

    f32x2 dk2 = (f32x2){0.f, 0.f};
    if (MODE == 1) { dk2[0] = Dsk[c]; dk2[1] = Dsk[c + 1]; }

    f32x2 acc[16], kreg[16];
    #pragma unroll
    for (int i = 0; i < 16; ++i) acc[i] = (f32x2){0.f, 0.f};
    const float* kbase = KT + (size_t)(KPAD + w0) * DM + c;
    #pragma unroll
    for (int s = 0; s < 16; ++s) kreg[s] = *(const f32x2*)(kbase + (size_t)s * DM);

    for (int jb = 0; jb <= t; ++jb) {
        const float* kb = KT + (size_t)(KPAD + w0 - jb * 16 - 1) * DM + c;
        const unsigned short* ub = row + (size_t)jb * 16 * DM;
        #pragma unroll
        for (int hb = 0; hb < 2; ++hb) {
            f32x2 kn2[8];
            unsigned us8[8];
            #pragma unroll
            for (int q = 0; q < 8; ++q) {
                kn2[q] = *(const f32x2*)(kb - (size_t)(hb * 8 + q) * DM);
                us8[q] = *(const unsigned*)(ub + (size_t)(hb * 8 + q) * DM);
            }
            #pragma unroll
            for (int jj2 = 0; jj2 < 8; ++jj2) {
                int jj = hb * 8 + jj2;
                f32x2 u2;
                u2[0] = __uint_as_float(us8[jj2] << 16);
                u2[1] = __uint_as_float(us8[jj2] & 0xffff0000u);
                #pragma unroll
                for (int i = 0; i < 16; ++i)
                    acc[i] = pkfma(kreg[(i - jj) & 15], u2, acc[i]);
                kreg[(15 - jj) & 15] = kn2[jj2];
            }
        }
    }

    if (MODE == 0) {
        #pragma unroll
        for (int i = 0; i < 16; ++i) {
            unsigned o = (unsigned)f2bf(acc[i][0]) | ((unsigned)f2bf(acc[i][1]) << 16);
            *(unsigned*)(out + ((size_t)((b << 7) | (w0 + i)) * SP + rr) * DM + c) = o;
        }
    } else {
        #pragma unroll
        for (int i = 0; i < 16; ++i) {
            int hh = w0 + i;
            unsigned hu = *(const unsigned*)(h + ((size_t)((b << 14) | (hh << 7) | rr)) * DM + c);
            float v0 = gelu_f(fmaf(__uint_as_float(hu << 16), dk2[0], acc[i][0]));
            float v1 = gelu_f(fmaf(__uint_as_float(hu & 0xffff0000u), dk2[1], acc[i][1]));
            unsigned o = (unsigned)f2bf(v0) | ((unsigned)f2bf(v1) << 16);
            *(unsigned*)(out + ((size_t)r * SP + hh) * DM + c) = o;
        }
    }
}

// ---------------------------------------------------------------------------
// GLU GEMM, barrier-free & LDS-free (r5/r9 math, verified). NEW: full af
// double-buffer -- all 8 next-strip fragment loads issued BEFORE the current
// strip's MFMA loop, giving a full strip (~300+ cy) of latency cover.
// 8 waves/block; wave wv holds persistent W frags for a-cols [wv*32,+32) AND
// g-cols [256+wv*32,+32). hp = (A@W_a+b_a)*sigmoid(A@W_g+b_g)+h, pos-order.
// ---------------------------------------------------------------------------
__global__ __launch_bounds__(512, 1) void glu_kernel(
        const unsigned short* __restrict__ Ab, const unsigned short* __restrict__ Bt,
        const unsigned short* __restrict__ h, unsigned short* __restrict__ hp,
        const float* __restrict__ bo) {
    int tid = threadIdx.x;
    int lane = tid & 63, wv = tid >> 6;
    int lc = lane & 15, g = lane >> 4;
    int m0 = blockIdx.x * 128;

    bf16x8 wf[4][8];
    #pragma unroll
    for (int cf = 0; cf < 4; ++cf) {
        int colb = (cf < 2) ? (wv * 32 + cf * 16) : (256 + wv * 32 + (cf - 2) * 16);
        #pragma unroll
        for (int kk = 0; kk < 8; ++kk)
            wf[cf][kk] = *(const bf16x8*)(Bt + (size_t)(colb + lc) * DM + kk * 32 + g * 8);
    }
    float4 ba[2], bg[2];
    #pragma unroll
    for (int cf = 0; cf < 2; ++cf) {
        ba[cf] = *(const float4*)(bo + wv * 32 + cf * 16 + g * 4);
        bg[cf] = *(const float4*)(bo + 256 + wv * 32 + cf * 16 + g * 4);
    }

    bf16x8 afA[8], afB[8];
    #pragma unroll
    for (int kk = 0; kk < 8; ++kk)
        afA[kk] = *(const bf16x8*)(Ab + (size_t)(m0 + lc) * DM + kk * 32 + g * 8);

#define GLU_STRIP(S, CUR, NXT)                                                  \
    {                                                                           \
        if (S < 7) {                                                            \
            _Pragma("unroll")                                                   \
            for (int kk = 0; kk < 8; ++kk)                                      \
                NXT[kk] = *(const bf16x8*)(Ab + (size_t)(m0 + (S + 1) * 16 + lc) * DM + kk * 32 + g * 8); \
        }                                                                       \
        int m = m0 + S * 16 + lc;                                               \
        int b_ = m >> 14, w_ = (m >> 7) & 127, hh_ = m & 127;                   \
        size_t pbase = ((size_t)((b_ << 14) | (hh_ << 7) | w_)) * DM + wv * 32 + g * 4; \
        uint2 hv0 = *(const uint2*)(h + pbase);                                 \
        uint2 hv1 = *(const uint2*)(h + pbase + 16);                            \
        f32x4 acc0 = (f32x4){0.f, 0.f, 0.f, 0.f};                               \
        f32x4 acc1 = acc0, acc2 = acc0, acc3 = acc0;                            \
        _Pragma("unroll")                                                       \
        for (int kk = 0; kk < 8; ++kk) {                                        \
            acc0 = __builtin_amdgcn_mfma_f32_16x16x32_bf16(wf[0][kk], CUR[kk], acc0, 0, 0, 0); \
            acc1 = __builtin_amdgcn_mfma_f32_16x16x32_bf16(wf[1][kk], CUR[kk], acc1, 0, 0, 0); \
            acc2 = __builtin_amdgcn_mfma_f32_16x16x32_bf16(wf[2][kk], CUR[kk], acc2, 0, 0, 0); \
            acc3 = __builtin_amdgcn_mfma_f32_16x16x32_bf16(wf[3][kk], CUR[kk], acc3, 0, 0, 0); \
        }                                                                       \
        float hr0[4], hr1[4];                                                   \
        hr0[0] = __uint_as_float(hv0.x << 16);                                  \
        hr0[1] = __uint_as_float(hv0.x & 0xffff0000u);                          \
        hr0[2] = __uint_as_float(hv0.y << 16);                                  \
        hr0[3] = __uint_as_float(hv0.y & 0xffff0000u);                          \
        hr1[0] = __uint_as_float(hv1.x << 16);                                  \
        hr1[1] = __uint_as_float(hv1.x & 0xffff0000u);                          \
        hr1[2] = __uint_as_float(hv1.y << 16);                                  \
        hr1[3] = __uint_as_float(hv1.y & 0xffff0000u);                          \
        float o0[4], o1[4];                                                     \
        _Pragma("unroll")                                                       \
        for (int reg = 0; reg < 4; ++reg) {                                     \
            o0[reg] = (acc0[reg] + (&ba[0].x)[reg]) * sigmoid_f(acc2[reg] + (&bg[0].x)[reg]) + hr0[reg]; \
            o1[reg] = (acc1[reg] + (&ba[1].x)[reg]) * sigmoid_f(acc3[reg] + (&bg[1].x)[reg]) + hr1[reg]; \
        }                                                                       \
        uint2 ov0, ov1;                                                         \
        ov0.x = (unsigned)f2bf(o0[0]) | ((unsigned)f2bf(o0[1]) << 16);          \
        ov0.y = (unsigned)f2bf(o0[2]) | ((unsigned)f2bf(o0[3]) << 16);          \
        ov1.x = (unsigned)f2bf(o1[0]) | ((unsigned)f2bf(o1[1]) << 16);          \
        ov1.y = (unsigned)f2bf(o1[2]) | ((unsigned)f2bf(o1[3]) << 16);          \
        *(uint2*)(hp + pbase) = ov0;                                            \
        *(uint2*)(hp + pbase + 16) = ov1;                                       \
    }

    GLU_STRIP(0, afA, afB)
    GLU_STRIP(1, afB, afA)
    GLU_STRIP(2, afA, afB)
    GLU_STRIP(3, afB, afA)
    GLU_STRIP(4, afA, afB)
    GLU_STRIP(5, afB, afA)
    GLU_STRIP(6, afA, afB)
    GLU_STRIP(7, afB, afA)
#undef GLU_STRIP
}

// ---------------------------------------------------------------------------
// LayerNorm: h = LN(hp) (bf16 -> bf16, pos-order). Wave = 1 row, lane = 4 ch.
// ---------------------------------------------------------------------------
__global__ __launch_bounds__(256) void ln_kernel(
        const unsigned short* __restrict__ hp, unsigned short* __restrict__ h,
        const float* __restrict__ lnw, const float* __restrict__ lnb) {
    int pos = blockIdx.x * 4 + (threadIdx.x >> 6);
    int lane = threadIdx.x & 63;
    size_t base = (size_t)pos * DM + lane * 4;
    uint2 hv = *(const uint2*)(hp + base);
    float v[4];
    v[0] = __uint_as_float(hv.x << 16);
    v[1] = __uint_as_float(hv.x & 0xffff0000u);
    v[2] = __uint_as_float(hv.y << 16);
    v[3] = __uint_as_float(hv.y & 0xffff0000u);
    float s1 = v[0] + v[1] + v[2] + v[3];
    float s2 = v[0] * v[0] + v[1] * v[1] + v[2] * v[2] + v[3] * v[3];
    #pragma unroll
    for (int off = 1; off < 64; off <<= 1) {
        s1 += __shfl_xor(s1, off);
        s2 += __shfl_xor(s2, off);
    }
    float mean = s1 * (1.0f / 256.0f);
    float var = s2 * (1.0f / 256.0f) - mean * mean;
    float inv = rsqrtf(var + 1e-5f);
    float4 w4 = *(const float4*)(lnw + lane * 4);
    float4 b4 = *(const float4*)(lnb + lane * 4);
    float o0 = (v[0] - mean) * inv * w4.x + b4.x;
    float o1 = (v[1] - mean) * inv * w4.y + b4.y;
    float o2 = (v[2] - mean) * inv * w4.z + b4.z;
    float o3 = (v[3] - mean) * inv * w4.w + b4.w;
    uint2 ov;
    ov.x = (unsigned)f2bf(o0) | ((unsigned)f2bf(o1) << 16);
    ov.y = (unsigned)f2bf(o2) | ((unsigned)f2bf(o3) << 16);
    *(uint2*)(h + base) = ov;
}

// ---------------------------------------------------------------------------
// Decoder: bf16 h in.
// ---------------------------------------------------------------------------
__global__ __launch_bounds__(256) void decode_kernel(
        const unsigned short* __restrict__ h, const float* __restrict__ Wd,
        const float* __restrict__ bd, float* __restrict__ out) {
    int pos = blockIdx.x * 4 + (threadIdx.x >> 6);
    int lane = threadIdx.x & 63;
    float s = 0.0f;
    #pragma unroll
    for (int j = 0; j < 4; ++j) {
        int d = j * 64 + lane;
        s += bf2f(h[(size_t)pos * DM + d]) * Wd[d];
    }
    #pragma unroll
    for (int off = 32; off > 0; off >>= 1) s += __shfl_down(s, off);
    if (lane == 0) out[pos] = s + bd[0];
}

// ---------------------------------------------------------------------------
extern "C" void kernel_launch(void* const* d_in, const int* in_sizes, int n_in,
                              void* d_out, int out_size, void* d_ws, size_t ws_size,
                              hipStream_t stream) {
    const float* x       = (const float*)d_in[0];
    const float* grid    = (const float*)d_in[1];
    const float* W_enc   = (const float*)d_in[2];
    const float* b_enc   = (const float*)d_in[3];
    const float* log_dt  = (const float*)d_in[4];
    const float* logA_re = (const float*)d_in[5];
    const float* A_im    = (const float*)d_in[6];
    const float* C_re    = (const float*)d_in[7];
    const float* C_im    = (const float*)d_in[8];
    const float* Dskip   = (const float*)d_in[9];
    const float* W_out   = (const float*)d_in[10];
    const float* b_out   = (const float*)d_in[11];
    const float* ln_w    = (const float*)d_in[12];
    const float* ln_b    = (const float*)d_in[13];
    const float* W_dec   = (const float*)d_in[14];
    const float* b_dec   = (const float*)d_in[15];

    char* base = (char*)d_ws;
    float*          K_Tp = (float*)base;                              // 1,310,720 B
    unsigned short* hbuf = (unsigned short*)(base + 1310720);         // 33,554,432 B
    unsigned short* T16  = (unsigned short*)(base + 34865152);        // 33,554,432 B
    unsigned short* Abuf = (unsigned short*)(base + 68419584);        // 33,554,432 B
    unsigned short* Bt   = (unsigned short*)(base + 101974016);       // 1,048,576 B
    unsigned short* hp   = T16;    // reuse: T16 dead after conv_h

    hipMemsetAsync(K_Tp, 0, (size_t)8 * KROWS * DM * sizeof(float), stream);
    gen_k_kernel<<<dim3(8 * DM), dim3(128), 0, stream>>>(log_dt, logA_re, A_im,
                                                         C_re, C_im, K_Tp);
    prep_b_kernel<<<dim3(2048), dim3(256), 0, stream>>>(W_out, Bt);
    encode_kernel<<<dim3(2048), dim3(256), 0, stream>>>(x, grid, W_enc, b_enc, hbuf);

    for (int l = 0; l < 4; ++l) {
        const float* Kh = K_Tp + (size_t)(l * 2 + 0) * KROWS * DM;
        const float* Kw = K_Tp + (size_t)(l * 2 + 1) * KROWS * DM;
        conv_kernel<0><<<dim3(2048), dim3(256), 0, stream>>>(hbuf, T16, Kw,
                                                             (const unsigned short*)nullptr, (const float*)nullptr);
        conv_kernel<1><<<dim3(2048), dim3(256), 0, stream>>>(T16, Abuf, Kh,
                                                             hbuf, Dskip + (size_t)l * DM);
        glu_kernel<<<dim3(512), dim3(512), 0, stream>>>(Abuf,
            Bt + (size_t)l * 131072, hbuf, hp, b_out + (size_t)l * 512);
        ln_kernel<<<dim3(16384), dim3(256), 0, stream>>>(hp, hbuf,
            ln_w + (size_t)l * DM, ln_b + (size_t)l * DM);
    }

    decode_kernel<<<dim3(16384), dim3(256), 0, stream>>>(hbuf, W_dec, b_dec,
                                                         (float*)d_out);
}

// Round 11
// 770.020 us; speedup vs baseline: 1.2726x; 1.0836x over previous
//
#include <hip/hip_runtime.h>
#include <math.h>

#define DM 256          // d_model
#define NS 64           // N state
#define SP 128          // spatial H == W

typedef __attribute__((ext_vector_type(8))) short bf16x8;
typedef __attribute__((ext_vector_type(4))) float f32x4;

__device__ __forceinline__ float gelu_f(float x) {
    float x3 = x * x * x;
    return 0.5f * x * (1.0f + tanhf(0.7978845608028654f * (x + 0.044715f * x3)));
}
__device__ __forceinline__ float sigmoid_f(float x) {
    return 1.0f / (1.0f + expf(-x));
}
__device__ __forceinline__ unsigned short f2bf(float f) {   // RNE f32->bf16
    unsigned u = __float_as_uint(f);
    u += 0x7fff + ((u >> 16) & 1);
    return (unsigned short)(u >> 16);
}
__device__ __forceinline__ float bf2f(unsigned short b) {
    return __uint_as_float(((unsigned)b) << 16);
}

// ---------------------------------------------------------------------------
// S4D tap generation -> Kd[la][d][q] fp32 (r6 verbatim, verified).
// ---------------------------------------------------------------------------
__global__ __launch_bounds__(128) void gen_k_kernel(
        const float* __restrict__ log_dt, const float* __restrict__ logA_re,
        const float* __restrict__ A_im,   const float* __restrict__ C_re,
        const float* __restrict__ C_im,   float* __restrict__ Kd) {
    int blk = blockIdx.x;
    int d  = blk & (DM - 1);
    int la = blk >> 8;
    int q  = threadIdx.x;
    __shared__ float s_cbr[NS], s_cbi[NS], s_dr[NS], s_di[NS];
    int pbase = (la * DM + d) * NS;
    float dt = expf(log_dt[la * DM + d]);
    if (q < NS) {
        int n = q;
        float ar = -expf(logA_re[pbase + n]);
        float ai = A_im[pbase + n];
        float dr = dt * ar, di = dt * ai;
        float er = expf(dr);
        float sn, cs;
        sincosf(di, &sn, &cs);
        float nr = er * cs - 1.0f, ni = er * sn;
        float inv = 1.0f / (ar * ar + ai * ai);
        float br = (nr * ar + ni * ai) * inv;
        float bi = (ni * ar - nr * ai) * inv;
        float cr = C_re[pbase + n], ci = C_im[pbase + n];
        s_cbr[n] = cr * br - ci * bi;
        s_cbi[n] = cr * bi + ci * br;
        s_dr[n] = dr;
        s_di[n] = di;
    }
    __syncthreads();
    float fq = (float)q;
    float acc = 0.0f;
    for (int n = 0; n < NS; ++n) {
        float pr = expf(s_dr[n] * fq);
        float sn, cs;
        sincosf(s_di[n] * fq, &sn, &cs);
        acc += s_cbr[n] * (pr * cs) - s_cbi[n] * (pr * sn);
    }
    Kd[((size_t)la * DM + d) * SP + q] = 2.0f * acc;
}

// ---------------------------------------------------------------------------
// Toeplitz build (per layer, r6 verbatim): Tp[axis][d][i][j] = k[i-j] (j<=i).
// ---------------------------------------------------------------------------
__global__ __launch_bounds__(256) void toep_kernel(
        const float* __restrict__ Kd, unsigned short* __restrict__ Tp, int l) {
    int blk = blockIdx.x;
    int axis = blk >> 8, d = blk & 255;
    int la = l * 2 + axis;
    __shared__ float kt[SP];
    if (threadIdx.x < SP) kt[threadIdx.x] = Kd[((size_t)la * DM + d) * SP + threadIdx.x];
    __syncthreads();
    size_t bse = ((size_t)axis * DM + d) * 16384;
    for (int e = threadIdx.x; e < 16384; e += 256) {
        int i = e >> 7, j = e & 127;
        Tp[bse + e] = (j <= i) ? f2bf(kt[i - j]) : (unsigned short)0;
    }
}

// ---------------------------------------------------------------------------
// W_out fp32 [l][k=256][n=512] -> Bt bf16 [l][n=512][k=256]
// ---------------------------------------------------------------------------
__global__ __launch_bounds__(256) void prep_b_kernel(
        const float* __restrict__ Wo, unsigned short* __restrict__ Bt) {
    int idx = blockIdx.x * 256 + threadIdx.x;
    int l = idx >> 17, rem = idx & 131071, n = rem >> 8, k = rem & 255;
    Bt[idx] = f2bf(Wo[(size_t)l * 131072 + k * 512 + n]);
}

// ---------------------------------------------------------------------------
// Encoder -> bf16 h_p (pos-major), packed pair stores (r10 verbatim).
// ---------------------------------------------------------------------------
__global__ __launch_bounds__(256) void encode_kernel(
        const float* __restrict__ x, const float* __restrict__ g,
        const float* __restrict__ W_enc, const float* __restrict__ b_enc,
        unsigned short* __restrict__ h) {
    int total = 4 * SP * SP * 128;   // channel pairs
    for (int idx = blockIdx.x * blockDim.x + threadIdx.x; idx < total;
         idx += gridDim.x * blockDim.x) {
        int c = (idx & 127) * 2;
        int pos = idx >> 7;
        float xv = x[pos], gv = g[pos];
        float v0 = xv * W_enc[c] + gv * W_enc[DM + c] + b_enc[c];
        float v1 = xv * W_enc[c + 1] + gv * W_enc[DM + c + 1] + b_enc[c + 1];
        unsigned o = (unsigned)f2bf(v0) | ((unsigned)f2bf(v1) << 16);
        *(unsigned*)(h + (size_t)pos * DM + c) = o;
    }
}

// ---------------------------------------------------------------------------
// Generic 64x64-tile ushort transpose: in [Ri][Ci] -> out [Ci][Ri].
// 4B-per-element LDS tile (bank-conflict-free both phases, 2-way max).
// rt = bid >> ctshift, ct = bid & ctmask; grid = (Ri/64)*(Ci/64).
// ---------------------------------------------------------------------------
__global__ __launch_bounds__(256) void transpose_kernel(
        const unsigned short* __restrict__ in, unsigned short* __restrict__ out,
        int Ci, int Ri, int ctmask, int ctshift) {
    __shared__ unsigned tile[64][65];
    int bid = blockIdx.x;
    int rt = bid >> ctshift, ct = bid & ctmask;
    int r0 = rt << 6, c0 = ct << 6;
    int tid = threadIdx.x;
    #pragma unroll
    for (int rep = 0; rep < 2; ++rep) {
        int e = rep * 256 + tid;
        int p = e >> 3, cc = e & 7;
        uint4 v = *(const uint4*)(in + (size_t)(r0 + p) * Ci + c0 + cc * 8);
        const unsigned short* pv = (const unsigned short*)&v;
        #pragma unroll
        for (int q = 0; q < 8; ++q) tile[p][cc * 8 + q] = pv[q];
    }
    __syncthreads();
    #pragma unroll
    for (int rep = 0; rep < 2; ++rep) {
        int e = rep * 256 + tid;
        int cc = e >> 3, pc = e & 7;
        unsigned short tmp[8];
        #pragma unroll
        for (int q = 0; q < 8; ++q) tmp[q] = (unsigned short)tile[pc * 8 + q][cc];
        *(uint4*)(out + (size_t)(c0 + cc) * Ri + r0 + pc * 8) = *(const uint4*)tmp;
    }
}

// ---------------------------------------------------------------------------
// Fused separable conv via MFMA (r6-verified math; I/O fixed):
// block = (d, b): U (LDS) <- h_c contiguous 16B loads; GEMM1 M1 = U @ TpW^T
// (B-frags global, double-buffered); M1T (LDS); GEMM2 Z^T = M1T @ TpH^T;
// epilogue gelu(Z + U*Dsk) -> LDS linearize -> coalesced A_c store.
// XOR-chunk-swizzled LDS (r6 scheme). 8 waves, VGPR~110 @ 4 waves/SIMD.
// ---------------------------------------------------------------------------
__global__ __launch_bounds__(512, 4) void conv_kernel(
        const unsigned short* __restrict__ hc, const unsigned short* __restrict__ Tp,
        unsigned short* __restrict__ Ac, const float* __restrict__ Dsk) {
    __shared__ unsigned short U[128][128];     // [hh][w], chunk^=(hh&7)
    __shared__ unsigned short M1T[128][128];   // [w][hh], chunk^=(w&7)
    int bid = blockIdx.x;
    int d = bid >> 2, b = bid & 3;
    int tid = threadIdx.x;
    int lane = tid & 63, wv = tid >> 6;        // 8 waves
    int lc = lane & 15, g = lane >> 4;

    const unsigned short* TpW = Tp + (size_t)(DM + d) * 16384;  // axis 1 (W)
    const unsigned short* TpH = Tp + (size_t)d * 16384;         // axis 0 (H)

    // GEMM1 kk=0 B-frags issued before staging (latency overlaps staging)
    bf16x8 bcur[8], bnxt[8];
    #pragma unroll
    for (int ni = 0; ni < 8; ++ni)
        bcur[ni] = *(const bf16x8*)(TpW + (size_t)(ni * 16 + lc) * 128 + g * 8);

    // ---- stage U: contiguous 16B loads, swizzled LDS writes
    {
        const uint4* src = (const uint4*)(hc + ((size_t)d * 4 + b) * 16384);
        #pragma unroll
        for (int it = 0; it < 4; ++it) {
            int e = it * 512 + tid;            // 2048 uint4 chunks
            int hh = e >> 4, wc = e & 15;
            uint4 v = src[e];
            *(uint4*)&U[hh][((wc ^ (hh & 7)) << 3)] = v;
        }
    }
    __syncthreads();

    // ---- GEMM1: M1[hh,w] = sum_j U[hh,j]*kw[w-j]  -> M1T[w][hh] (LDS)
    {
        f32x4 acc[8];
        #pragma unroll
        for (int ni = 0; ni < 8; ++ni) acc[ni] = (f32x4){0.f, 0.f, 0.f, 0.f};
        #pragma unroll
        for (int kk = 0; kk < 4; ++kk) {
            if (kk < 3) {
                #pragma unroll
                for (int ni = 0; ni < 8; ++ni)
                    bnxt[ni] = *(const bf16x8*)(TpW + (size_t)(ni * 16 + lc) * 128 + (kk + 1) * 32 + g * 8);
            } else {   // prefetch GEMM2's kk=0 B-frags (TpH)
                #pragma unroll
                for (int ni = 0; ni < 8; ++ni)
                    bnxt[ni] = *(const bf16x8*)(TpH + (size_t)(ni * 16 + lc) * 128 + g * 8);
            }
            int hh = wv * 16 + lc;
            bf16x8 a = *(const bf16x8*)&U[hh][(((kk * 4 + g) ^ (hh & 7)) << 3)];
            #pragma unroll
            for (int ni = 0; ni < 8; ++ni)
                acc[ni] = __builtin_amdgcn_mfma_f32_16x16x32_bf16(a, bcur[ni], acc[ni], 0, 0, 0);
            #pragma unroll
            for (int ni = 0; ni < 8; ++ni) bcur[ni] = bnxt[ni];
        }
        int hh0 = wv * 16 + g * 4;
        #pragma unroll
        for (int ni = 0; ni < 8; ++ni) {
            int w = ni * 16 + lc;
            ushort4 p;
            p.x = f2bf(acc[ni][0]); p.y = f2bf(acc[ni][1]);
            p.z = f2bf(acc[ni][2]); p.w = f2bf(acc[ni][3]);
            *(ushort4*)&M1T[w][((((hh0 >> 3) ^ (w & 7)) << 3) | (hh0 & 7))] = p;
        }
    }
    __syncthreads();

    // ---- GEMM2: ZT[w,hh] = sum_{h'} M1T[w,h']*kh[hh-h'] ; epilogue
    {
        f32x4 acc[8];
        #pragma unroll
        for (int ni = 0; ni < 8; ++ni) acc[ni] = (f32x4){0.f, 0.f, 0.f, 0.f};
        #pragma unroll
        for (int kk = 0; kk < 4; ++kk) {
            if (kk < 3) {
                #pragma unroll
                for (int ni = 0; ni < 8; ++ni)
                    bnxt[ni] = *(const bf16x8*)(TpH + (size_t)(ni * 16 + lc) * 128 + (kk + 1) * 32 + g * 8);
            }
            int w = wv * 16 + lc;
            bf16x8 a = *(const bf16x8*)&M1T[w][(((kk * 4 + g) ^ (w & 7)) << 3)];
            #pragma unroll
            for (int ni = 0; ni < 8; ++ni)
                acc[ni] = __builtin_amdgcn_mfma_f32_16x16x32_bf16(a, bcur[ni], acc[ni], 0, 0, 0);
            #pragma unroll
            for (int ni = 0; ni < 8; ++ni) bcur[ni] = bnxt[ni];
        }
        // epilogue: Z^T[w][hh]: w = wv*16+g*4+reg, hh = ni*16+lc
        float dk = Dsk[d];
        int w0 = wv * 16 + g * 4;
        ushort4 zo[8];
        #pragma unroll
        for (int ni = 0; ni < 8; ++ni) {
            int hh = ni * 16 + lc;
            ushort4 hu = *(const ushort4*)&U[hh][((((w0 >> 3) ^ (hh & 7)) << 3) | (w0 & 7))];
            zo[ni].x = f2bf(gelu_f(fmaf(bf2f(hu.x), dk, acc[ni][0])));
            zo[ni].y = f2bf(gelu_f(fmaf(bf2f(hu.y), dk, acc[ni][1])));
            zo[ni].z = f2bf(gelu_f(fmaf(bf2f(hu.z), dk, acc[ni][2])));
            zo[ni].w = f2bf(gelu_f(fmaf(bf2f(hu.w), dk, acc[ni][3])));
        }
        __syncthreads();   // all U/M1T reads complete
        #pragma unroll
        for (int ni = 0; ni < 8; ++ni) {
            int hh = ni * 16 + lc;
            *(ushort4*)&U[hh][((((w0 >> 3) ^ (hh & 7)) << 3) | (w0 & 7))] = zo[ni];
        }
    }
    __syncthreads();

    // ---- coalesced copy-out (unswizzle)
    {
        uint4* dst = (uint4*)(Ac + ((size_t)d * 4 + b) * 16384);
        #pragma unroll
        for (int it = 0; it < 4; ++it) {
            int e = it * 512 + tid;
            int hh = e >> 4, wc = e & 15;
            dst[e] = *(const uint4*)&U[hh][((wc ^ (hh & 7)) << 3)];
        }
    }
}

// ---------------------------------------------------------------------------
// GLU GEMM, barrier/LDS-free, af double-buffered (r10 verbatim except index:
// A_p rows are now (b,hh,w) = pos order, so pbase = m*DM directly).
// hp = (A@W_a+b_a)*sigmoid(A@W_g+b_g)+h, pos-major bf16.
// ---------------------------------------------------------------------------
__global__ __launch_bounds__(512, 1) void glu_kernel(
        const unsigned short* __restrict__ Ab, const unsigned short* __restrict__ Bt,
        const unsigned short* __restrict__ h, unsigned short* __restrict__ hp,
        const float* __restrict__ bo) {
    int tid = threadIdx.x;
    int lane = tid & 63, wv = tid >> 6;
    int lc = lane & 15, g = lane >> 4;
    int m0 = blockIdx.x * 128;

    bf16x8 wf[4][8];
    #pragma unroll
    for (int cf = 0; cf < 4; ++cf) {
        int colb = (cf < 2) ? (wv * 32 + cf * 16) : (256 + wv * 32 + (cf - 2) * 16);
        #pragma unroll
        for (int kk = 0; kk < 8; ++kk)
            wf[cf][kk] = *(const bf16x8*)(Bt + (size_t)(colb + lc) * DM + kk * 32 + g * 8);
    }
    float4 ba[2], bg[2];
    #pragma unroll
    for (int cf = 0; cf < 2; ++cf) {
        ba[cf] = *(const float4*)(bo + wv * 32 + cf * 16 + g * 4);
        bg[cf] = *(const float4*)(bo + 256 + wv * 32 + cf * 16 + g * 4);
    }

    bf16x8 afA[8], afB[8];
    #pragma unroll
    for (int kk = 0; kk < 8; ++kk)
        afA[kk] = *(const bf16x8*)(Ab + (size_t)(m0 + lc) * DM + kk * 32 + g * 8);

#define GLU_STRIP(S, CUR, NXT)                                                  \
    {                                                                           \
        if (S < 7) {                                                            \
            _Pragma("unroll")                                                   \
            for (int kk = 0; kk < 8; ++kk)                                      \
                NXT[kk] = *(const bf16x8*)(Ab + (size_t)(m0 + (S + 1) * 16 + lc) * DM + kk * 32 + g * 8); \
        }                                                                       \
        int m = m0 + S * 16 + lc;                                               \
        size_t pbase = (size_t)m * DM + wv * 32 + g * 4;                        \
        uint2 hv0 = *(const uint2*)(h + pbase);                                 \
        uint2 hv1 = *(const uint2*)(h + pbase + 16);                            \
        f32x4 acc0 = (f32x4){0.f, 0.f, 0.f, 0.f};                               \
        f32x4 acc1 = acc0, acc2 = acc0, acc3 = acc0;                            \
        _Pragma("unroll")                                                       \
        for (int kk = 0; kk < 8; ++kk) {                                        \
            acc0 = __builtin_amdgcn_mfma_f32_16x16x32_bf16(wf[0][kk], CUR[kk], acc0, 0, 0, 0); \
            acc1 = __builtin_amdgcn_mfma_f32_16x16x32_bf16(wf[1][kk], CUR[kk], acc1, 0, 0, 0); \
            acc2 = __builtin_amdgcn_mfma_f32_16x16x32_bf16(wf[2][kk], CUR[kk], acc2, 0, 0, 0); \
            acc3 = __builtin_amdgcn_mfma_f32_16x16x32_bf16(wf[3][kk], CUR[kk], acc3, 0, 0, 0); \
        }                                                                       \
        float hr0[4], hr1[4];                                                   \
        hr0[0] = __uint_as_float(hv0.x << 16);                                  \
        hr0[1] = __uint_as_float(hv0.x & 0xffff0000u);                          \
        hr0[2] = __uint_as_float(hv0.y << 16);                                  \
        hr0[3] = __uint_as_float(hv0.y & 0xffff0000u);                          \
        hr1[0] = __uint_as_float(hv1.x << 16);                                  \
        hr1[1] = __uint_as_float(hv1.x & 0xffff0000u);                          \
        hr1[2] = __uint_as_float(hv1.y << 16);                                  \
        hr1[3] = __uint_as_float(hv1.y & 0xffff0000u);                          \
        float o0[4], o1[4];                                                     \
        _Pragma("unroll")                                                       \
        for (int reg = 0; reg < 4; ++reg) {                                     \
            o0[reg] = (acc0[reg] + (&ba[0].x)[reg]) * sigmoid_f(acc2[reg] + (&bg[0].x)[reg]) + hr0[reg]; \
            o1[reg] = (acc1[reg] + (&ba[1].x)[reg]) * sigmoid_f(acc3[reg] + (&bg[1].x)[reg]) + hr1[reg]; \
        }                                                                       \
        uint2 ov0, ov1;                                                         \
        ov0.x = (unsigned)f2bf(o0[0]) | ((unsigned)f2bf(o0[1]) << 16);          \
        ov0.y = (unsigned)f2bf(o0[2]) | ((unsigned)f2bf(o0[3]) << 16);          \
        ov1.x = (unsigned)f2bf(o1[0]) | ((unsigned)f2bf(o1[1]) << 16);          \
        ov1.y = (unsigned)f2bf(o1[2]) | ((unsigned)f2bf(o1[3]) << 16);          \
        *(uint2*)(hp + pbase) = ov0;                                            \
        *(uint2*)(hp + pbase + 16) = ov1;                                       \
    }

    GLU_STRIP(0, afA, afB)
    GLU_STRIP(1, afB, afA)
    GLU_STRIP(2, afA, afB)
    GLU_STRIP(3, afB, afA)
    GLU_STRIP(4, afA, afB)
    GLU_STRIP(5, afB, afA)
    GLU_STRIP(6, afA, afB)
    GLU_STRIP(7, afB, afA)
#undef GLU_STRIP
}

// ---------------------------------------------------------------------------
// LayerNorm: h_p = LN(hp) (bf16 -> bf16, pos-order). Wave = 1 row.
// ---------------------------------------------------------------------------
__global__ __launch_bounds__(256) void ln_kernel(
        const unsigned short* __restrict__ hp, unsigned short* __restrict__ h,
        const float* __restrict__ lnw, const float* __restrict__ lnb) {
    int pos = blockIdx.x * 4 + (threadIdx.x >> 6);
    int lane = threadIdx.x & 63;
    size_t base = (size_t)pos * DM + lane * 4;
    uint2 hv = *(const uint2*)(hp + base);
    float v[4];
    v[0] = __uint_as_float(hv.x << 16);
    v[1] = __uint_as_float(hv.x & 0xffff0000u);
    v[2] = __uint_as_float(hv.y << 16);
    v[3] = __uint_as_float(hv.y & 0xffff0000u);
    float s1 = v[0] + v[1] + v[2] + v[3];
    float s2 = v[0] * v[0] + v[1] * v[1] + v[2] * v[2] + v[3] * v[3];
    #pragma unroll
    for (int off = 1; off < 64; off <<= 1) {
        s1 += __shfl_xor(s1, off);
        s2 += __shfl_xor(s2, off);
    }
    float mean = s1 * (1.0f / 256.0f);
    float var = s2 * (1.0f / 256.0f) - mean * mean;
    float inv = rsqrtf(var + 1e-5f);
    float4 w4 = *(const float4*)(lnw + lane * 4);
    float4 b4 = *(const float4*)(lnb + lane * 4);
    float o0 = (v[0] - mean) * inv * w4.x + b4.x;
    float o1 = (v[1] - mean) * inv * w4.y + b4.y;
    float o2 = (v[2] - mean) * inv * w4.z + b4.z;
    float o3 = (v[3] - mean) * inv * w4.w + b4.w;
    uint2 ov;
    ov.x = (unsigned)f2bf(o0) | ((unsigned)f2bf(o1) << 16);
    ov.y = (unsigned)f2bf(o2) | ((unsigned)f2bf(o3) << 16);
    *(uint2*)(h + base) = ov;
}

// ---------------------------------------------------------------------------
// Decoder: bf16 h_p in.
// ---------------------------------------------------------------------------
__global__ __launch_bounds__(256) void decode_kernel(
        const unsigned short* __restrict__ h, const float* __restrict__ Wd,
        const float* __restrict__ bd, float* __restrict__ out) {
    int pos = blockIdx.x * 4 + (threadIdx.x >> 6);
    int lane = threadIdx.x & 63;
    float s = 0.0f;
    #pragma unroll
    for (int j = 0; j < 4; ++j) {
        int d = j * 64 + lane;
        s += bf2f(h[(size_t)pos * DM + d]) * Wd[d];
    }
    #pragma unroll
    for (int off = 32; off > 0; off >>= 1) s += __shfl_down(s, off);
    if (lane == 0) out[pos] = s + bd[0];
}

// ---------------------------------------------------------------------------
extern "C" void kernel_launch(void* const* d_in, const int* in_sizes, int n_in,
                              void* d_out, int out_size, void* d_ws, size_t ws_size,
                              hipStream_t stream) {
    const float* x       = (const float*)d_in[0];
    const float* grid    = (const float*)d_in[1];
    const float* W_enc   = (const float*)d_in[2];
    const float* b_enc   = (const float*)d_in[3];
    const float* log_dt  = (const float*)d_in[4];
    const float* logA_re = (const float*)d_in[5];
    const float* A_im    = (const float*)d_in[6];
    const float* C_re    = (const float*)d_in[7];
    const float* C_im    = (const float*)d_in[8];
    const float* Dskip   = (const float*)d_in[9];
    const float* W_out   = (const float*)d_in[10];
    const float* b_out   = (const float*)d_in[11];
    const float* ln_w    = (const float*)d_in[12];
    const float* ln_b    = (const float*)d_in[13];
    const float* W_dec   = (const float*)d_in[14];
    const float* b_dec   = (const float*)d_in[15];

    char* base = (char*)d_ws;
    float*          Kd  = (float*)base;                            //  1,048,576 B
    unsigned short* Bt  = (unsigned short*)(base + 1048576);       //  1,048,576 B
    unsigned short* hP  = (unsigned short*)(base + 2097152);       // 33,554,432 B (pos-major h)
    unsigned short* R1  = (unsigned short*)(base + 35651584);      // 33,554,432 B (h_c, then A_p)
    unsigned short* R2  = (unsigned short*)(base + 69206016);      // 33,554,432 B (A_c, then hp)
    unsigned short* Tp  = (unsigned short*)(base + 102760448);     // 16,777,216 B (per-layer Toeplitz)

    gen_k_kernel<<<dim3(8 * DM), dim3(128), 0, stream>>>(log_dt, logA_re, A_im,
                                                         C_re, C_im, Kd);
    prep_b_kernel<<<dim3(2048), dim3(256), 0, stream>>>(W_out, Bt);
    encode_kernel<<<dim3(2048), dim3(256), 0, stream>>>(x, grid, W_enc, b_enc, hP);

    for (int l = 0; l < 4; ++l) {
        toep_kernel<<<dim3(512), dim3(256), 0, stream>>>(Kd, Tp, l);
        // h_p [65536][256] -> h_c [256][65536]
        transpose_kernel<<<dim3(4096), dim3(256), 0, stream>>>(hP, R1, 256, 65536, 3, 2);
        conv_kernel<<<dim3(1024), dim3(512), 0, stream>>>(R1, Tp, R2,
                                                          Dskip + (size_t)l * DM);
        // A_c [256][65536] -> A_p [65536][256]
        transpose_kernel<<<dim3(4096), dim3(256), 0, stream>>>(R2, R1, 65536, 256, 1023, 10);
        glu_kernel<<<dim3(512), dim3(512), 0, stream>>>(R1,
            Bt + (size_t)l * 131072, hP, R2, b_out + (size_t)l * 512);
        ln_kernel<<<dim3(16384), dim3(256), 0, stream>>>(R2, hP,
            ln_w + (size_t)l * DM, ln_b + (size_t)l * DM);
    }

    decode_kernel<<<dim3(16384), dim3(256), 0, stream>>>(hP, W_dec, b_dec,
                                                         (float*)d_out);
}

// Round 12
// 718.456 us; speedup vs baseline: 1.3640x; 1.0718x over previous
//
#include <hip/hip_runtime.h>
#include <math.h>

#define DM 256          // d_model
#define NS 64           // N state
#define SP 128          // spatial H == W

typedef __attribute__((ext_vector_type(8))) short bf16x8;
typedef __attribute__((ext_vector_type(4))) float f32x4;

__device__ __forceinline__ float gelu_f(float x) {
    float x3 = x * x * x;
    return 0.5f * x * (1.0f + tanhf(0.7978845608028654f * (x + 0.044715f * x3)));
}
__device__ __forceinline__ float sigmoid_f(float x) {
    return 1.0f / (1.0f + expf(-x));
}
__device__ __forceinline__ unsigned short f2bf(float f) {   // RNE f32->bf16
    unsigned u = __float_as_uint(f);
    u += 0x7fff + ((u >> 16) & 1);
    return (unsigned short)(u >> 16);
}
__device__ __forceinline__ float bf2f(unsigned short b) {
    return __uint_as_float(((unsigned)b) << 16);
}

// ---------------------------------------------------------------------------
// S4D tap generation -> Kd[la][d][q] fp32 (verified).
// ---------------------------------------------------------------------------
__global__ __launch_bounds__(128) void gen_k_kernel(
        const float* __restrict__ log_dt, const float* __restrict__ logA_re,
        const float* __restrict__ A_im,   const float* __restrict__ C_re,
        const float* __restrict__ C_im,   float* __restrict__ Kd) {
    int blk = blockIdx.x;
    int d  = blk & (DM - 1);
    int la = blk >> 8;
    int q  = threadIdx.x;
    __shared__ float s_cbr[NS], s_cbi[NS], s_dr[NS], s_di[NS];
    int pbase = (la * DM + d) * NS;
    float dt = expf(log_dt[la * DM + d]);
    if (q < NS) {
        int n = q;
        float ar = -expf(logA_re[pbase + n]);
        float ai = A_im[pbase + n];
        float dr = dt * ar, di = dt * ai;
        float er = expf(dr);
        float sn, cs;
        sincosf(di, &sn, &cs);
        float nr = er * cs - 1.0f, ni = er * sn;
        float inv = 1.0f / (ar * ar + ai * ai);
        float br = (nr * ar + ni * ai) * inv;
        float bi = (ni * ar - nr * ai) * inv;
        float cr = C_re[pbase + n], ci = C_im[pbase + n];
        s_cbr[n] = cr * br - ci * bi;
        s_cbi[n] = cr * bi + ci * br;
        s_dr[n] = dr;
        s_di[n] = di;
    }
    __syncthreads();
    float fq = (float)q;
    float acc = 0.0f;
    for (int n = 0; n < NS; ++n) {
        float pr = expf(s_dr[n] * fq);
        float sn, cs;
        sincosf(s_di[n] * fq, &sn, &cs);
        acc += s_cbr[n] * (pr * cs) - s_cbi[n] * (pr * sn);
    }
    Kd[((size_t)la * DM + d) * SP + q] = 2.0f * acc;
}

// ---------------------------------------------------------------------------
// Toeplitz build (per layer): Tp[axis][d][i][j] = k[i-j] (j<=i), bf16.
// ---------------------------------------------------------------------------
__global__ __launch_bounds__(256) void toep_kernel(
        const float* __restrict__ Kd, unsigned short* __restrict__ Tp, int l) {
    int blk = blockIdx.x;
    int axis = blk >> 8, d = blk & 255;
    int la = l * 2 + axis;
    __shared__ float kt[SP];
    if (threadIdx.x < SP) kt[threadIdx.x] = Kd[((size_t)la * DM + d) * SP + threadIdx.x];
    __syncthreads();
    size_t bse = ((size_t)axis * DM + d) * 16384;
    for (int e = threadIdx.x; e < 16384; e += 256) {
        int i = e >> 7, j = e & 127;
        Tp[bse + e] = (j <= i) ? f2bf(kt[i - j]) : (unsigned short)0;
    }
}

// ---------------------------------------------------------------------------
// W_out fp32 [l][k=256][n=512] -> Bt bf16 [l][n=512][k=256]
// ---------------------------------------------------------------------------
__global__ __launch_bounds__(256) void prep_b_kernel(
        const float* __restrict__ Wo, unsigned short* __restrict__ Bt) {
    int idx = blockIdx.x * 256 + threadIdx.x;
    int l = idx >> 17, rem = idx & 131071, n = rem >> 8, k = rem & 255;
    Bt[idx] = f2bf(Wo[(size_t)l * 131072 + k * 512 + n]);
}

// ---------------------------------------------------------------------------
// Encoder -> bf16 h_p (pos-major), packed pair stores.
// ---------------------------------------------------------------------------
__global__ __launch_bounds__(256) void encode_kernel(
        const float* __restrict__ x, const float* __restrict__ g,
        const float* __restrict__ W_enc, const float* __restrict__ b_enc,
        unsigned short* __restrict__ h) {
    int total = 4 * SP * SP * 128;   // channel pairs
    for (int idx = blockIdx.x * blockDim.x + threadIdx.x; idx < total;
         idx += gridDim.x * blockDim.x) {
        int c = (idx & 127) * 2;
        int pos = idx >> 7;
        float xv = x[pos], gv = g[pos];
        float v0 = xv * W_enc[c] + gv * W_enc[DM + c] + b_enc[c];
        float v1 = xv * W_enc[c + 1] + gv * W_enc[DM + c + 1] + b_enc[c + 1];
        unsigned o = (unsigned)f2bf(v0) | ((unsigned)f2bf(v1) << 16);
        *(unsigned*)(h + (size_t)pos * DM + c) = o;
    }
}

// ---------------------------------------------------------------------------
// Generic 64x64-tile ushort transpose: in [Ri? rows][Ci] -> out [Ci-idx][Ri].
// FUSE=1 additionally applies out = gelu(in^T + Dsk[d]*hres) (c2p A-build).
// ---------------------------------------------------------------------------
template <int FUSE>
__global__ __launch_bounds__(256) void transpose_kernel(
        const unsigned short* __restrict__ in, unsigned short* __restrict__ out,
        int Ci, int Ri, int ctmask, int ctshift,
        const unsigned short* __restrict__ hres, const float* __restrict__ Dsk) {
    __shared__ unsigned tile[64][65];
    int bid = blockIdx.x;
    int rt = bid >> ctshift, ct = bid & ctmask;
    int r0 = rt << 6, c0 = ct << 6;
    int tid = threadIdx.x;
    #pragma unroll
    for (int rep = 0; rep < 2; ++rep) {
        int e = rep * 256 + tid;
        int p = e >> 3, cc = e & 7;
        uint4 v = *(const uint4*)(in + (size_t)(r0 + p) * Ci + c0 + cc * 8);
        const unsigned short* pv = (const unsigned short*)&v;
        #pragma unroll
        for (int q = 0; q < 8; ++q) tile[p][cc * 8 + q] = pv[q];
    }
    __syncthreads();
    #pragma unroll
    for (int rep = 0; rep < 2; ++rep) {
        int e = rep * 256 + tid;
        int cc = e >> 3, pc = e & 7;
        unsigned short tmp[8];
        #pragma unroll
        for (int q = 0; q < 8; ++q) tmp[q] = (unsigned short)tile[pc * 8 + q][cc];
        size_t oaddr = (size_t)(c0 + cc) * Ri + r0 + pc * 8;
        if (FUSE) {
            int d0 = r0 + pc * 8;
            uint4 hv = *(const uint4*)(hres + oaddr);
            const unsigned short* hvp = (const unsigned short*)&hv;
            float4 dk0 = *(const float4*)(Dsk + d0);
            float4 dk1 = *(const float4*)(Dsk + d0 + 4);
            #pragma unroll
            for (int q = 0; q < 8; ++q) {
                float dk = (q < 4) ? (&dk0.x)[q] : (&dk1.x)[q - 4];
                float z = fmaf(bf2f(hvp[q]), dk, bf2f(tmp[q]));
                tmp[q] = f2bf(gelu_f(z));
            }
        }
        *(uint4*)(out + oaddr) = *(const uint4*)tmp;
    }
}

// ---------------------------------------------------------------------------
// Separable conv via MFMA, all operands in LDS (the r3-r11 lesson: never feed
// MFMA from registers holding >8 outstanding global loads).
// Block = (d,b), XCD-grouped. LDS 64KB: Tile (U -> M1T -> Z, aliased) +
// TpL (TpW -> TpH). All tiles XOR-chunk swizzled (2-way max).
// GEMM1: M1[hh][w'] = sum_w U[hh][w]*TpW[w'][w]; GEMM2: Z^T[w][hh'] =
// sum_hh M1T[w][hh]*TpH[hh'][hh]. Output: raw Z_c (skip+gelu fused into c2p).
// VGPR ~70 -> 4 waves/SIMD at 2 blocks/CU.
// ---------------------------------------------------------------------------
__global__ __launch_bounds__(512, 4) void conv_kernel(
        const unsigned short* __restrict__ hc, const unsigned short* __restrict__ Tp,
        unsigned short* __restrict__ Zc) {
    __shared__ unsigned short Tile[128][128];
    __shared__ unsigned short TpL[128][128];
    int bid = blockIdx.x;
    int work = (bid & 7) * 128 + (bid >> 3);   // XCD-grouped: d-siblings share L2
    int d = work >> 2, b = work & 3;
    int tid = threadIdx.x;
    int lane = tid & 63, wv = tid >> 6;        // 8 waves
    int lc = lane & 15, g = lane >> 4;

    const unsigned short* TpW = Tp + (size_t)(DM + d) * 16384;  // axis 1 (W)
    const unsigned short* TpH = Tp + (size_t)d * 16384;         // axis 0 (H)

    // ---- stage U and TpW (coalesced 16B, swizzled LDS)
    {
        const uint4* srcU = (const uint4*)(hc + ((size_t)d * 4 + b) * 16384);
        const uint4* srcT = (const uint4*)TpW;
        #pragma unroll
        for (int it = 0; it < 4; ++it) {
            int e = it * 512 + tid;
            int r = e >> 4, wc = e & 15;
            *(uint4*)&Tile[r][((wc ^ (r & 7)) << 3)] = srcU[e];
            *(uint4*)&TpL[r][((wc ^ (r & 7)) << 3)] = srcT[e];
        }
    }
    __syncthreads();

    f32x4 acc[8];
    // ---- GEMM1
    #pragma unroll
    for (int ni = 0; ni < 8; ++ni) acc[ni] = (f32x4){0.f, 0.f, 0.f, 0.f};
    #pragma unroll
    for (int kk = 0; kk < 4; ++kk) {
        int hh = wv * 16 + lc;
        bf16x8 a = *(const bf16x8*)&Tile[hh][(((kk * 4 + g) ^ (hh & 7)) << 3)];
        #pragma unroll
        for (int ni = 0; ni < 8; ++ni) {
            int n = ni * 16 + lc;
            bf16x8 bf = *(const bf16x8*)&TpL[n][(((kk * 4 + g) ^ (n & 7)) << 3)];
            acc[ni] = __builtin_amdgcn_mfma_f32_16x16x32_bf16(a, bf, acc[ni], 0, 0, 0);
        }
    }
    __syncthreads();   // all GEMM1 LDS reads complete

    // ---- write M1T into Tile (over U); stage TpH into TpL (over TpW)
    {
        int hh0 = wv * 16 + g * 4;
        #pragma unroll
        for (int ni = 0; ni < 8; ++ni) {
            int w = ni * 16 + lc;
            ushort4 p;
            p.x = f2bf(acc[ni][0]); p.y = f2bf(acc[ni][1]);
            p.z = f2bf(acc[ni][2]); p.w = f2bf(acc[ni][3]);
            *(ushort4*)&Tile[w][((((hh0 >> 3) ^ (w & 7)) << 3) | (hh0 & 7))] = p;
        }
        const uint4* srcT = (const uint4*)TpH;
        #pragma unroll
        for (int it = 0; it < 4; ++it) {
            int e = it * 512 + tid;
            int r = e >> 4, wc = e & 15;
            *(uint4*)&TpL[r][((wc ^ (r & 7)) << 3)] = srcT[e];
        }
    }
    __syncthreads();

    // ---- GEMM2
    #pragma unroll
    for (int ni = 0; ni < 8; ++ni) acc[ni] = (f32x4){0.f, 0.f, 0.f, 0.f};
    #pragma unroll
    for (int kk = 0; kk < 4; ++kk) {
        int w = wv * 16 + lc;
        bf16x8 a = *(const bf16x8*)&Tile[w][(((kk * 4 + g) ^ (w & 7)) << 3)];
        #pragma unroll
        for (int ni = 0; ni < 8; ++ni) {
            int n = ni * 16 + lc;
            bf16x8 bf = *(const bf16x8*)&TpL[n][(((kk * 4 + g) ^ (n & 7)) << 3)];
            acc[ni] = __builtin_amdgcn_mfma_f32_16x16x32_bf16(a, bf, acc[ni], 0, 0, 0);
        }
    }
    __syncthreads();   // all GEMM2 LDS reads complete

    // ---- write Z[hh][w] into Tile (transpose via frag indices), copy out
    {
        int w0 = wv * 16 + g * 4;
        #pragma unroll
        for (int ni = 0; ni < 8; ++ni) {
            int hh = ni * 16 + lc;
            ushort4 p;
            p.x = f2bf(acc[ni][0]); p.y = f2bf(acc[ni][1]);
            p.z = f2bf(acc[ni][2]); p.w = f2bf(acc[ni][3]);
            *(ushort4*)&Tile[hh][((((w0 >> 3) ^ (hh & 7)) << 3) | (w0 & 7))] = p;
        }
    }
    __syncthreads();
    {
        uint4* dst = (uint4*)(Zc + ((size_t)d * 4 + b) * 16384);
        #pragma unroll
        for (int it = 0; it < 4; ++it) {
            int e = it * 512 + tid;
            int r = e >> 4, wc = e & 15;
            dst[e] = *(const uint4*)&Tile[r][((wc ^ (r & 7)) << 3)];
        }
    }
}

// ---------------------------------------------------------------------------
// GLU GEMM, lean-split: wave owns 16 a-cols + 16 g-cols (wa/wg = 64 VGPR),
// single af buffer with in-loop next-strip reload. Grid = 512 m-blocks x 2
// col-halves. ~135 VGPR @ 3 waves/SIMD. Barrier/LDS-free.
// hp = (A@W_a+b_a)*sigmoid(A@W_g+b_g) + h, pos-major bf16.
// ---------------------------------------------------------------------------
__global__ __launch_bounds__(512, 3) void glu_kernel(
        const unsigned short* __restrict__ Ab, const unsigned short* __restrict__ Bt,
        const unsigned short* __restrict__ h, unsigned short* __restrict__ hp,
        const float* __restrict__ bo) {
    int tid = threadIdx.x;
    int lane = tid & 63, wv = tid >> 6;
    int lc = lane & 15, g = lane >> 4;
    int halfn = blockIdx.x & 1;
    int m0 = (blockIdx.x >> 1) * 128;
    int ca = (halfn * 8 + wv) * 16;
    int cg = 256 + ca;

    bf16x8 wa[8], wg[8];
    #pragma unroll
    for (int kk = 0; kk < 8; ++kk) {
        wa[kk] = *(const bf16x8*)(Bt + (size_t)(ca + lc) * DM + kk * 32 + g * 8);
        wg[kk] = *(const bf16x8*)(Bt + (size_t)(cg + lc) * DM + kk * 32 + g * 8);
    }
    float4 ba = *(const float4*)(bo + ca + g * 4);
    float4 bgv = *(const float4*)(bo + cg + g * 4);

    bf16x8 af[8];
    #pragma unroll
    for (int kk = 0; kk < 8; ++kk)
        af[kk] = *(const bf16x8*)(Ab + (size_t)(m0 + lc) * DM + kk * 32 + g * 8);

    #pragma unroll
    for (int s = 0; s < 8; ++s) {
        size_t pbase = (size_t)(m0 + s * 16 + lc) * DM + ca + g * 4;
        uint2 hv = *(const uint2*)(h + pbase);
        f32x4 aa = (f32x4){0.f, 0.f, 0.f, 0.f};
        f32x4 ag = aa;
        #pragma unroll
        for (int kk = 0; kk < 8; ++kk) {
            aa = __builtin_amdgcn_mfma_f32_16x16x32_bf16(wa[kk], af[kk], aa, 0, 0, 0);
            ag = __builtin_amdgcn_mfma_f32_16x16x32_bf16(wg[kk], af[kk], ag, 0, 0, 0);
            if (s < 7)
                af[kk] = *(const bf16x8*)(Ab + (size_t)(m0 + (s + 1) * 16 + lc) * DM + kk * 32 + g * 8);
        }
        float hr[4];
        hr[0] = __uint_as_float(hv.x << 16);
        hr[1] = __uint_as_float(hv.x & 0xffff0000u);
        hr[2] = __uint_as_float(hv.y << 16);
        hr[3] = __uint_as_float(hv.y & 0xffff0000u);
        float o[4];
        #pragma unroll
        for (int reg = 0; reg < 4; ++reg)
            o[reg] = (aa[reg] + (&ba.x)[reg]) * sigmoid_f(ag[reg] + (&bgv.x)[reg]) + hr[reg];
        uint2 ov;
        ov.x = (unsigned)f2bf(o[0]) | ((unsigned)f2bf(o[1]) << 16);
        ov.y = (unsigned)f2bf(o[2]) | ((unsigned)f2bf(o[3]) << 16);
        *(uint2*)(hp + pbase) = ov;
    }
}

// ---------------------------------------------------------------------------
// LayerNorm: h_p = LN(hp) (bf16 -> bf16, pos-order). Wave = 1 row.
// ---------------------------------------------------------------------------
__global__ __launch_bounds__(256) void ln_kernel(
        const unsigned short* __restrict__ hp, unsigned short* __restrict__ h,
        const float* __restrict__ lnw, const float* __restrict__ lnb) {
    int pos = blockIdx.x * 4 + (threadIdx.x >> 6);
    int lane = threadIdx.x & 63;
    size_t base = (size_t)pos * DM + lane * 4;
    uint2 hv = *(const uint2*)(hp + base);
    float v[4];
    v[0] = __uint_as_float(hv.x << 16);
    v[1] = __uint_as_float(hv.x & 0xffff0000u);
    v[2] = __uint_as_float(hv.y << 16);
    v[3] = __uint_as_float(hv.y & 0xffff0000u);
    float s1 = v[0] + v[1] + v[2] + v[3];
    float s2 = v[0] * v[0] + v[1] * v[1] + v[2] * v[2] + v[3] * v[3];
    #pragma unroll
    for (int off = 1; off < 64; off <<= 1) {
        s1 += __shfl_xor(s1, off);
        s2 += __shfl_xor(s2, off);
    }
    float mean = s1 * (1.0f / 256.0f);
    float var = s2 * (1.0f / 256.0f) - mean * mean;
    float inv = rsqrtf(var + 1e-5f);
    float4 w4 = *(const float4*)(lnw + lane * 4);
    float4 b4 = *(const float4*)(lnb + lane * 4);
    float o0 = (v[0] - mean) * inv * w4.x + b4.x;
    float o1 = (v[1] - mean) * inv * w4.y + b4.y;
    float o2 = (v[2] - mean) * inv * w4.z + b4.z;
    float o3 = (v[3] - mean) * inv * w4.w + b4.w;
    uint2 ov;
    ov.x = (unsigned)f2bf(o0) | ((unsigned)f2bf(o1) << 16);
    ov.y = (unsigned)f2bf(o2) | ((unsigned)f2bf(o3) << 16);
    *(uint2*)(h + base) = ov;
}

// ---------------------------------------------------------------------------
// Decoder: bf16 h_p in.
// ---------------------------------------------------------------------------
__global__ __launch_bounds__(256) void decode_kernel(
        const unsigned short* __restrict__ h, const float* __restrict__ Wd,
        const float* __restrict__ bd, float* __restrict__ out) {
    int pos = blockIdx.x * 4 + (threadIdx.x >> 6);
    int lane = threadIdx.x & 63;
    float s = 0.0f;
    #pragma unroll
    for (int j = 0; j < 4; ++j) {
        int d = j * 64 + lane;
        s += bf2f(h[(size_t)pos * DM + d]) * Wd[d];
    }
    #pragma unroll
    for (int off = 32; off > 0; off >>= 1) s += __shfl_down(s, off);
    if (lane == 0) out[pos] = s + bd[0];
}

// ---------------------------------------------------------------------------
extern "C" void kernel_launch(void* const* d_in, const int* in_sizes, int n_in,
                              void* d_out, int out_size, void* d_ws, size_t ws_size,
                              hipStream_t stream) {
    const float* x       = (const float*)d_in[0];
    const float* grid    = (const float*)d_in[1];
    const float* W_enc   = (const float*)d_in[2];
    const float* b_enc   = (const float*)d_in[3];
    const float* log_dt  = (const float*)d_in[4];
    const float* logA_re = (const float*)d_in[5];
    const float* A_im    = (const float*)d_in[6];
    const float* C_re    = (const float*)d_in[7];
    const float* C_im    = (const float*)d_in[8];
    const float* Dskip   = (const float*)d_in[9];
    const float* W_out   = (const float*)d_in[10];
    const float* b_out   = (const float*)d_in[11];
    const float* ln_w    = (const float*)d_in[12];
    const float* ln_b    = (const float*)d_in[13];
    const float* W_dec   = (const float*)d_in[14];
    const float* b_dec   = (const float*)d_in[15];

    char* base = (char*)d_ws;
    float*          Kd  = (float*)base;                            //  1,048,576 B
    unsigned short* Bt  = (unsigned short*)(base + 1048576);       //  1,048,576 B
    unsigned short* hP  = (unsigned short*)(base + 2097152);       // 33,554,432 B
    unsigned short* R1  = (unsigned short*)(base + 35651584);      // 33,554,432 B (h_c, then A_p)
    unsigned short* R2  = (unsigned short*)(base + 69206016);      // 33,554,432 B (Z_c, then hp)
    unsigned short* Tp  = (unsigned short*)(base + 102760448);     // 16,777,216 B

    gen_k_kernel<<<dim3(8 * DM), dim3(128), 0, stream>>>(log_dt, logA_re, A_im,
                                                         C_re, C_im, Kd);
    prep_b_kernel<<<dim3(2048), dim3(256), 0, stream>>>(W_out, Bt);
    encode_kernel<<<dim3(2048), dim3(256), 0, stream>>>(x, grid, W_enc, b_enc, hP);

    for (int l = 0; l < 4; ++l) {
        toep_kernel<<<dim3(512), dim3(256), 0, stream>>>(Kd, Tp, l);
        // h_p [65536][256] -> h_c [256][65536]
        transpose_kernel<0><<<dim3(4096), dim3(256), 0, stream>>>(
            hP, R1, 256, 65536, 3, 2, (const unsigned short*)nullptr, (const float*)nullptr);
        conv_kernel<<<dim3(1024), dim3(512), 0, stream>>>(R1, Tp, R2);
        // Z_c [256][65536] -> A_p [65536][256] with fused gelu(Z + Dsk*h)
        transpose_kernel<1><<<dim3(4096), dim3(256), 0, stream>>>(
            R2, R1, 65536, 256, 1023, 10, hP, Dskip + (size_t)l * DM);
        glu_kernel<<<dim3(1024), dim3(512), 0, stream>>>(R1,
            Bt + (size_t)l * 131072, hP, R2, b_out + (size_t)l * 512);
        ln_kernel<<<dim3(16384), dim3(256), 0, stream>>>(R2, hP,
            ln_w + (size_t)l * DM, ln_b + (size_t)l * DM);
    }

    decode_kernel<<<dim3(16384), dim3(256), 0, stream>>>(hP, W_dec, b_dec,
                                                         (float*)d_out);
}

// Round 13
// 512.032 us; speedup vs baseline: 1.9139x; 1.4031x over previous
//
#include <hip/hip_runtime.h>
#include <math.h>

#define DM 256          // d_model
#define NS 64           // N state
#define SP 128          // spatial H == W

typedef __attribute__((ext_vector_type(8))) short bf16x8;
typedef __attribute__((ext_vector_type(4))) float f32x4;

__device__ __forceinline__ float gelu_f(float x) {
    float x3 = x * x * x;
    return 0.5f * x * (1.0f + tanhf(0.7978845608028654f * (x + 0.044715f * x3)));
}
__device__ __forceinline__ float sigmoid_f(float x) {
    return 1.0f / (1.0f + expf(-x));
}
__device__ __forceinline__ unsigned short f2bf(float f) {   // RNE f32->bf16
    unsigned u = __float_as_uint(f);
    u += 0x7fff + ((u >> 16) & 1);
    return (unsigned short)(u >> 16);
}
__device__ __forceinline__ float bf2f(unsigned short b) {
    return __uint_as_float(((unsigned)b) << 16);
}

// ---------------------------------------------------------------------------
// S4D tap generation -> Kd[la][d][q] fp32 (verified).
// ---------------------------------------------------------------------------
__global__ __launch_bounds__(128) void gen_k_kernel(
        const float* __restrict__ log_dt, const float* __restrict__ logA_re,
        const float* __restrict__ A_im,   const float* __restrict__ C_re,
        const float* __restrict__ C_im,   float* __restrict__ Kd) {
    int blk = blockIdx.x;
    int d  = blk & (DM - 1);
    int la = blk >> 8;
    int q  = threadIdx.x;
    __shared__ float s_cbr[NS], s_cbi[NS], s_dr[NS], s_di[NS];
    int pbase = (la * DM + d) * NS;
    float dt = expf(log_dt[la * DM + d]);
    if (q < NS) {
        int n = q;
        float ar = -expf(logA_re[pbase + n]);
        float ai = A_im[pbase + n];
        float dr = dt * ar, di = dt * ai;
        float er = expf(dr);
        float sn, cs;
        sincosf(di, &sn, &cs);
        float nr = er * cs - 1.0f, ni = er * sn;
        float inv = 1.0f / (ar * ar + ai * ai);
        float br = (nr * ar + ni * ai) * inv;
        float bi = (ni * ar - nr * ai) * inv;
        float cr = C_re[pbase + n], ci = C_im[pbase + n];
        s_cbr[n] = cr * br - ci * bi;
        s_cbi[n] = cr * bi + ci * br;
        s_dr[n] = dr;
        s_di[n] = di;
    }
    __syncthreads();
    float fq = (float)q;
    float acc = 0.0f;
    for (int n = 0; n < NS; ++n) {
        float pr = expf(s_dr[n] * fq);
        float sn, cs;
        sincosf(s_di[n] * fq, &sn, &cs);
        acc += s_cbr[n] * (pr * cs) - s_cbi[n] * (pr * sn);
    }
    Kd[((size_t)la * DM + d) * SP + q] = 2.0f * acc;
}

// ---------------------------------------------------------------------------
// Toeplitz build (per layer): Tp[axis][d][i][j] = k[i-j] (j<=i), bf16.
// ---------------------------------------------------------------------------
__global__ __launch_bounds__(256) void toep_kernel(
        const float* __restrict__ Kd, unsigned short* __restrict__ Tp, int l) {
    int blk = blockIdx.x;
    int axis = blk >> 8, d = blk & 255;
    int la = l * 2 + axis;
    __shared__ float kt[SP];
    if (threadIdx.x < SP) kt[threadIdx.x] = Kd[((size_t)la * DM + d) * SP + threadIdx.x];
    __syncthreads();
    size_t bse = ((size_t)axis * DM + d) * 16384;
    for (int e = threadIdx.x; e < 16384; e += 256) {
        int i = e >> 7, j = e & 127;
        Tp[bse + e] = (j <= i) ? f2bf(kt[i - j]) : (unsigned short)0;
    }
}

// ---------------------------------------------------------------------------
// W_out fp32 [l][k=256][n=512] -> Bt bf16 [l][n=512][k=256]
// ---------------------------------------------------------------------------
__global__ __launch_bounds__(256) void prep_b_kernel(
        const float* __restrict__ Wo, unsigned short* __restrict__ Bt) {
    int idx = blockIdx.x * 256 + threadIdx.x;
    int l = idx >> 17, rem = idx & 131071, n = rem >> 8, k = rem & 255;
    Bt[idx] = f2bf(Wo[(size_t)l * 131072 + k * 512 + n]);
}

// ---------------------------------------------------------------------------
// Encoder -> bf16 h_p (pos-major), packed pair stores.
// ---------------------------------------------------------------------------
__global__ __launch_bounds__(256) void encode_kernel(
        const float* __restrict__ x, const float* __restrict__ g,
        const float* __restrict__ W_enc, const float* __restrict__ b_enc,
        unsigned short* __restrict__ h) {
    int total = 4 * SP * SP * 128;   // channel pairs
    for (int idx = blockIdx.x * blockDim.x + threadIdx.x; idx < total;
         idx += gridDim.x * blockDim.x) {
        int c = (idx & 127) * 2;
        int pos = idx >> 7;
        float xv = x[pos], gv = g[pos];
        float v0 = xv * W_enc[c] + gv * W_enc[DM + c] + b_enc[c];
        float v1 = xv * W_enc[c + 1] + gv * W_enc[DM + c + 1] + b_enc[c + 1];
        unsigned o = (unsigned)f2bf(v0) | ((unsigned)f2bf(v1) << 16);
        *(unsigned*)(h + (size_t)pos * DM + c) = o;
    }
}

// ---------------------------------------------------------------------------
// Generic 64x64-tile ushort transpose: in [Ri rows][Ci] -> out [Ci][Ri].
// FUSE=1 additionally applies out = gelu(in^T + Dsk[d]*hres) (c2p A-build).
// ---------------------------------------------------------------------------
template <int FUSE>
__global__ __launch_bounds__(256) void transpose_kernel(
        const unsigned short* __restrict__ in, unsigned short* __restrict__ out,
        int Ci, int Ri, int ctmask, int ctshift,
        const unsigned short* __restrict__ hres, const float* __restrict__ Dsk) {
    __shared__ unsigned tile[64][65];
    int bid = blockIdx.x;
    int rt = bid >> ctshift, ct = bid & ctmask;
    int r0 = rt << 6, c0 = ct << 6;
    int tid = threadIdx.x;
    #pragma unroll
    for (int rep = 0; rep < 2; ++rep) {
        int e = rep * 256 + tid;
        int p = e >> 3, cc = e & 7;
        uint4 v = *(const uint4*)(in + (size_t)(r0 + p) * Ci + c0 + cc * 8);
        const unsigned short* pv = (const unsigned short*)&v;
        #pragma unroll
        for (int q = 0; q < 8; ++q) tile[p][cc * 8 + q] = pv[q];
    }
    __syncthreads();
    #pragma unroll
    for (int rep = 0; rep < 2; ++rep) {
        int e = rep * 256 + tid;
        int cc = e >> 3, pc = e & 7;
        unsigned short tmp[8];
        #pragma unroll
        for (int q = 0; q < 8; ++q) tmp[q] = (unsigned short)tile[pc * 8 + q][cc];
        size_t oaddr = (size_t)(c0 + cc) * Ri + r0 + pc * 8;
        if (FUSE) {
            int d0 = r0 + pc * 8;
            uint4 hv = *(const uint4*)(hres + oaddr);
            const unsigned short* hvp = (const unsigned short*)&hv;
            float4 dk0 = *(const float4*)(Dsk + d0);
            float4 dk1 = *(const float4*)(Dsk + d0 + 4);
            #pragma unroll
            for (int q = 0; q < 8; ++q) {
                float dk = (q < 4) ? (&dk0.x)[q] : (&dk1.x)[q - 4];
                float z = fmaf(bf2f(hvp[q]), dk, bf2f(tmp[q]));
                tmp[q] = f2bf(gelu_f(z));
            }
        }
        *(uint4*)(out + oaddr) = *(const uint4*)tmp;
    }
}

// ---------------------------------------------------------------------------
// Separable conv via MFMA, all operands in LDS (r12 verbatim, verified).
// ---------------------------------------------------------------------------
__global__ __launch_bounds__(512, 4) void conv_kernel(
        const unsigned short* __restrict__ hc, const unsigned short* __restrict__ Tp,
        unsigned short* __restrict__ Zc) {
    __shared__ unsigned short Tile[128][128];
    __shared__ unsigned short TpL[128][128];
    int bid = blockIdx.x;
    int work = (bid & 7) * 128 + (bid >> 3);   // XCD-grouped: d-siblings share L2
    int d = work >> 2, b = work & 3;
    int tid = threadIdx.x;
    int lane = tid & 63, wv = tid >> 6;        // 8 waves
    int lc = lane & 15, g = lane >> 4;

    const unsigned short* TpW = Tp + (size_t)(DM + d) * 16384;  // axis 1 (W)
    const unsigned short* TpH = Tp + (size_t)d * 16384;         // axis 0 (H)

    {
        const uint4* srcU = (const uint4*)(hc + ((size_t)d * 4 + b) * 16384);
        const uint4* srcT = (const uint4*)TpW;
        #pragma unroll
        for (int it = 0; it < 4; ++it) {
            int e = it * 512 + tid;
            int r = e >> 4, wc = e & 15;
            *(uint4*)&Tile[r][((wc ^ (r & 7)) << 3)] = srcU[e];
            *(uint4*)&TpL[r][((wc ^ (r & 7)) << 3)] = srcT[e];
        }
    }
    __syncthreads();

    f32x4 acc[8];
    #pragma unroll
    for (int ni = 0; ni < 8; ++ni) acc[ni] = (f32x4){0.f, 0.f, 0.f, 0.f};
    #pragma unroll
    for (int kk = 0; kk < 4; ++kk) {
        int hh = wv * 16 + lc;
        bf16x8 a = *(const bf16x8*)&Tile[hh][(((kk * 4 + g) ^ (hh & 7)) << 3)];
        #pragma unroll
        for (int ni = 0; ni < 8; ++ni) {
            int n = ni * 16 + lc;
            bf16x8 bf = *(const bf16x8*)&TpL[n][(((kk * 4 + g) ^ (n & 7)) << 3)];
            acc[ni] = __builtin_amdgcn_mfma_f32_16x16x32_bf16(a, bf, acc[ni], 0, 0, 0);
        }
    }
    __syncthreads();

    {
        int hh0 = wv * 16 + g * 4;
        #pragma unroll
        for (int ni = 0; ni < 8; ++ni) {
            int w = ni * 16 + lc;
            ushort4 p;
            p.x = f2bf(acc[ni][0]); p.y = f2bf(acc[ni][1]);
            p.z = f2bf(acc[ni][2]); p.w = f2bf(acc[ni][3]);
            *(ushort4*)&Tile[w][((((hh0 >> 3) ^ (w & 7)) << 3) | (hh0 & 7))] = p;
        }
        const uint4* srcT = (const uint4*)TpH;
        #pragma unroll
        for (int it = 0; it < 4; ++it) {
            int e = it * 512 + tid;
            int r = e >> 4, wc = e & 15;
            *(uint4*)&TpL[r][((wc ^ (r & 7)) << 3)] = srcT[e];
        }
    }
    __syncthreads();

    #pragma unroll
    for (int ni = 0; ni < 8; ++ni) acc[ni] = (f32x4){0.f, 0.f, 0.f, 0.f};
    #pragma unroll
    for (int kk = 0; kk < 4; ++kk) {
        int w = wv * 16 + lc;
        bf16x8 a = *(const bf16x8*)&Tile[w][(((kk * 4 + g) ^ (w & 7)) << 3)];
        #pragma unroll
        for (int ni = 0; ni < 8; ++ni) {
            int n = ni * 16 + lc;
            bf16x8 bf = *(const bf16x8*)&TpL[n][(((kk * 4 + g) ^ (n & 7)) << 3)];
            acc[ni] = __builtin_amdgcn_mfma_f32_16x16x32_bf16(a, bf, acc[ni], 0, 0, 0);
        }
    }
    __syncthreads();

    {
        int w0 = wv * 16 + g * 4;
        #pragma unroll
        for (int ni = 0; ni < 8; ++ni) {
            int hh = ni * 16 + lc;
            ushort4 p;
            p.x = f2bf(acc[ni][0]); p.y = f2bf(acc[ni][1]);
            p.z = f2bf(acc[ni][2]); p.w = f2bf(acc[ni][3]);
            *(ushort4*)&Tile[hh][((((w0 >> 3) ^ (hh & 7)) << 3) | (w0 & 7))] = p;
        }
    }
    __syncthreads();
    {
        uint4* dst = (uint4*)(Zc + ((size_t)d * 4 + b) * 16384);
        #pragma unroll
        for (int it = 0; it < 4; ++it) {
            int e = it * 512 + tid;
            int r = e >> 4, wc = e & 15;
            dst[e] = *(const uint4*)&Tile[r][((wc ^ (r & 7)) << 3)];
        }
    }
}

// ---------------------------------------------------------------------------
// GLU GEMM, LDS-staged (the r12-conv recipe applied to the GLU):
// block = 128 m-rows x all 512 cols, 8 waves (wave = 16 rows).
// A frags: 32 VGPR/lane, loaded ONCE per block (A read once total).
// Per col-quarter qp: stage a-cols [qp*64,+64) -> Ba, g-cols [256+qp*64,+64)
// -> Bg (32KB each, XOR-chunk swizzled, coalesced linear copy, B L2-hot);
// barrier; 64 MFMA (B-frag first operand -> lane holds 1 row x 4 contiguous
// cols); GLU + residual epilogue for the quarter; barrier.
// acc = aa[4]+ag[4] = 32 VGPR; total ~100 -> 4 waves/SIMD at 2 blocks/CU.
// hp = (A@W_a+b_a)*sigmoid(A@W_g+b_g) + h, pos-major bf16.
// ---------------------------------------------------------------------------
__global__ __launch_bounds__(512, 4) void glu_kernel(
        const unsigned short* __restrict__ Ab, const unsigned short* __restrict__ Bt,
        const unsigned short* __restrict__ h, unsigned short* __restrict__ hp,
        const float* __restrict__ bo) {
    __shared__ unsigned short Ba[64][256];   // a-col quarter, chunk^=(r&7)
    __shared__ unsigned short Bg[64][256];   // g-col quarter
    int tid = threadIdx.x;
    int lane = tid & 63, wv = tid >> 6;      // 8 waves
    int lc = lane & 15, g = lane >> 4;
    int m0 = blockIdx.x * 128;
    int mrow = m0 + wv * 16 + lc;

    // A fragments for this wave's 16 rows, full K (loaded once)
    bf16x8 af[8];
    #pragma unroll
    for (int kk = 0; kk < 8; ++kk)
        af[kk] = *(const bf16x8*)(Ab + (size_t)mrow * DM + kk * 32 + g * 8);

    #pragma unroll
    for (int qp = 0; qp < 4; ++qp) {
        // ---- stage B quarter pair (coalesced 16B, swizzled LDS)
        {
            const uint4* srcA = (const uint4*)(Bt + (size_t)(qp * 64) * DM);
            const uint4* srcG = (const uint4*)(Bt + (size_t)(256 + qp * 64) * DM);
            #pragma unroll
            for (int it = 0; it < 4; ++it) {
                int e = it * 512 + tid;          // 2048 chunks of 16B (64 rows x 32)
                int r = e >> 5, wc = e & 31;
                *(uint4*)&Ba[r][((wc ^ (r & 7)) << 3)] = srcA[e];
                *(uint4*)&Bg[r][((wc ^ (r & 7)) << 3)] = srcG[e];
            }
        }
        __syncthreads();

        f32x4 aa[4], ag[4];
        #pragma unroll
        for (int ni = 0; ni < 4; ++ni) {
            aa[ni] = (f32x4){0.f, 0.f, 0.f, 0.f};
            ag[ni] = (f32x4){0.f, 0.f, 0.f, 0.f};
        }
        #pragma unroll
        for (int kk = 0; kk < 8; ++kk) {
            #pragma unroll
            for (int ni = 0; ni < 4; ++ni) {
                int r = ni * 16 + lc;
                int ch = (((kk * 4 + g) ^ (r & 7)) << 3);
                bf16x8 bfa = *(const bf16x8*)&Ba[r][ch];
                bf16x8 bfg = *(const bf16x8*)&Bg[r][ch];
                aa[ni] = __builtin_amdgcn_mfma_f32_16x16x32_bf16(bfa, af[kk], aa[ni], 0, 0, 0);
                ag[ni] = __builtin_amdgcn_mfma_f32_16x16x32_bf16(bfg, af[kk], ag[ni], 0, 0, 0);
            }
        }

        // ---- epilogue: cols qp*64 + ni*16 + g*4 .. +4 for row mrow
        #pragma unroll
        for (int ni = 0; ni < 4; ++ni) {
            int ca = qp * 64 + ni * 16 + g * 4;
            float4 bav = *(const float4*)(bo + ca);
            float4 bgv = *(const float4*)(bo + 256 + ca);
            size_t pbase = (size_t)mrow * DM + ca;
            uint2 hv = *(const uint2*)(h + pbase);
            float hr[4];
            hr[0] = __uint_as_float(hv.x << 16);
            hr[1] = __uint_as_float(hv.x & 0xffff0000u);
            hr[2] = __uint_as_float(hv.y << 16);
            hr[3] = __uint_as_float(hv.y & 0xffff0000u);
            float o[4];
            #pragma unroll
            for (int reg = 0; reg < 4; ++reg)
                o[reg] = (aa[ni][reg] + (&bav.x)[reg]) * sigmoid_f(ag[ni][reg] + (&bgv.x)[reg]) + hr[reg];
            uint2 ov;
            ov.x = (unsigned)f2bf(o[0]) | ((unsigned)f2bf(o[1]) << 16);
            ov.y = (unsigned)f2bf(o[2]) | ((unsigned)f2bf(o[3]) << 16);
            *(uint2*)(hp + pbase) = ov;
        }
        __syncthreads();   // before next quarter overwrites Ba/Bg
    }
}

// ---------------------------------------------------------------------------
// LayerNorm: h_p = LN(hp) (bf16 -> bf16, pos-order). Wave = 1 row.
// ---------------------------------------------------------------------------
__global__ __launch_bounds__(256) void ln_kernel(
        const unsigned short* __restrict__ hp, unsigned short* __restrict__ h,
        const float* __restrict__ lnw, const float* __restrict__ lnb) {
    int pos = blockIdx.x * 4 + (threadIdx.x >> 6);
    int lane = threadIdx.x & 63;
    size_t base = (size_t)pos * DM + lane * 4;
    uint2 hv = *(const uint2*)(hp + base);
    float v[4];
    v[0] = __uint_as_float(hv.x << 16);
    v[1] = __uint_as_float(hv.x & 0xffff0000u);
    v[2] = __uint_as_float(hv.y << 16);
    v[3] = __uint_as_float(hv.y & 0xffff0000u);
    float s1 = v[0] + v[1] + v[2] + v[3];
    float s2 = v[0] * v[0] + v[1] * v[1] + v[2] * v[2] + v[3] * v[3];
    #pragma unroll
    for (int off = 1; off < 64; off <<= 1) {
        s1 += __shfl_xor(s1, off);
        s2 += __shfl_xor(s2, off);
    }
    float mean = s1 * (1.0f / 256.0f);
    float var = s2 * (1.0f / 256.0f) - mean * mean;
    float inv = rsqrtf(var + 1e-5f);
    float4 w4 = *(const float4*)(lnw + lane * 4);
    float4 b4 = *(const float4*)(lnb + lane * 4);
    float o0 = (v[0] - mean) * inv * w4.x + b4.x;
    float o1 = (v[1] - mean) * inv * w4.y + b4.y;
    float o2 = (v[2] - mean) * inv * w4.z + b4.z;
    float o3 = (v[3] - mean) * inv * w4.w + b4.w;
    uint2 ov;
    ov.x = (unsigned)f2bf(o0) | ((unsigned)f2bf(o1) << 16);
    ov.y = (unsigned)f2bf(o2) | ((unsigned)f2bf(o3) << 16);
    *(uint2*)(h + base) = ov;
}

// ---------------------------------------------------------------------------
// Decoder: bf16 h_p in.
// ---------------------------------------------------------------------------
__global__ __launch_bounds__(256) void decode_kernel(
        const unsigned short* __restrict__ h, const float* __restrict__ Wd,
        const float* __restrict__ bd, float* __restrict__ out) {
    int pos = blockIdx.x * 4 + (threadIdx.x >> 6);
    int lane = threadIdx.x & 63;
    float s = 0.0f;
    #pragma unroll
    for (int j = 0; j < 4; ++j) {
        int d = j * 64 + lane;
        s += bf2f(h[(size_t)pos * DM + d]) * Wd[d];
    }
    #pragma unroll
    for (int off = 32; off > 0; off >>= 1) s += __shfl_down(s, off);
    if (lane == 0) out[pos] = s + bd[0];
}

// ---------------------------------------------------------------------------
extern "C" void kernel_launch(void* const* d_in, const int* in_sizes, int n_in,
                              void* d_out, int out_size, void* d_ws, size_t ws_size,
                              hipStream_t stream) {
    const float* x       = (const float*)d_in[0];
    const float* grid    = (const float*)d_in[1];
    const float* W_enc   = (const float*)d_in[2];
    const float* b_enc   = (const float*)d_in[3];
    const float* log_dt  = (const float*)d_in[4];
    const float* logA_re = (const float*)d_in[5];
    const float* A_im    = (const float*)d_in[6];
    const float* C_re    = (const float*)d_in[7];
    const float* C_im    = (const float*)d_in[8];
    const float* Dskip   = (const float*)d_in[9];
    const float* W_out   = (const float*)d_in[10];
    const float* b_out   = (const float*)d_in[11];
    const float* ln_w    = (const float*)d_in[12];
    const float* ln_b    = (const float*)d_in[13];
    const float* W_dec   = (const float*)d_in[14];
    const float* b_dec   = (const float*)d_in[15];

    char* base = (char*)d_ws;
    float*          Kd  = (float*)base;                            //  1,048,576 B
    unsigned short* Bt  = (unsigned short*)(base + 1048576);       //  1,048,576 B
    unsigned short* hP  = (unsigned short*)(base + 2097152);       // 33,554,432 B
    unsigned short* R1  = (unsigned short*)(base + 35651584);      // 33,554,432 B (h_c, then A_p)
    unsigned short* R2  = (unsigned short*)(base + 69206016);      // 33,554,432 B (Z_c, then hp)
    unsigned short* Tp  = (unsigned short*)(base + 102760448);     // 16,777,216 B

    gen_k_kernel<<<dim3(8 * DM), dim3(128), 0, stream>>>(log_dt, logA_re, A_im,
                                                         C_re, C_im, Kd);
    prep_b_kernel<<<dim3(2048), dim3(256), 0, stream>>>(W_out, Bt);
    encode_kernel<<<dim3(2048), dim3(256), 0, stream>>>(x, grid, W_enc, b_enc, hP);

    for (int l = 0; l < 4; ++l) {
        toep_kernel<<<dim3(512), dim3(256), 0, stream>>>(Kd, Tp, l);
        // h_p [65536][256] -> h_c [256][65536]
        transpose_kernel<0><<<dim3(4096), dim3(256), 0, stream>>>(
            hP, R1, 256, 65536, 3, 2, (const unsigned short*)nullptr, (const float*)nullptr);
        conv_kernel<<<dim3(1024), dim3(512), 0, stream>>>(R1, Tp, R2);
        // Z_c [256][65536] -> A_p [65536][256] with fused gelu(Z + Dsk*h)
        transpose_kernel<1><<<dim3(4096), dim3(256), 0, stream>>>(
            R2, R1, 65536, 256, 1023, 10, hP, Dskip + (size_t)l * DM);
        glu_kernel<<<dim3(512), dim3(512), 0, stream>>>(R1,
            Bt + (size_t)l * 131072, hP, R2, b_out + (size_t)l * 512);
        ln_kernel<<<dim3(16384), dim3(256), 0, stream>>>(R2, hP,
            ln_w + (size_t)l * DM, ln_b + (size_t)l * DM);
    }

    decode_kernel<<<dim3(16384), dim3(256), 0, stream>>>(hP, W_dec, b_dec,
                                                         (float*)d_out);
}